// Round 10
// baseline (255.258 us; speedup 1.0000x reference)
//
#include <hip/hip_runtime.h>
#include <math.h>

// ---------------------------------------------------------------------------
// Problem constants
// ---------------------------------------------------------------------------
#define BS     8
#define LL     256
#define JJ     48
#define NN     32
#define TT     48
#define DM     512
#define DEMB   300
#define DFIX   30000
#define DEXT   32000
#define SRC_TOT (LL + JJ + NN)      // 336
#define ROWS   (BS * TT)            // 384
#define NT     235                  // logits n-tiles (235*128 = 30080)

typedef float f32x4  __attribute__((ext_vector_type(4)));
typedef short bf16x8 __attribute__((ext_vector_type(8)));

__device__ __forceinline__ short f2bf(float f) {
    union { float f; unsigned u; } v; v.f = f;
    return (short)((v.u + 0x7FFFu + ((v.u >> 16) & 1u)) >> 16);  // RNE
}
__device__ __forceinline__ float bf2f(short s) {
    union { unsigned u; float f; } v;
    v.u = ((unsigned)(unsigned short)s) << 16;
    return v.f;
}
__device__ __forceinline__ float fast_exp2(float x) {
#if __has_builtin(__builtin_amdgcn_exp2f)
    return __builtin_amdgcn_exp2f(x);
#else
    return exp2f(x);
#endif
}
__device__ __forceinline__ float fast_rcp(float x) {
#if __has_builtin(__builtin_amdgcn_rcpf)
    return __builtin_amdgcn_rcpf(x);
#else
    return 1.f / x;
#endif
}
__device__ __forceinline__ float fast_tanh(float x) {
    x = fminf(fmaxf(x, -15.f), 15.f);
    const float e = fast_exp2(x * 2.885390082f);
    return (e - 1.f) * fast_rcp(e + 1.f);
}
__device__ __forceinline__ bool smask_true(const void* smask, bool byteLayout, int i)
{
    if (byteLayout) return ((const unsigned char*)smask)[i] != 0;
    return ((const int*)smask)[i] != 0;
}
__device__ __forceinline__ void mask8(const void* smask, bool byteLayout, int i,
                                      int* mb)
{
    if (byteLayout) {
        const uchar4 a = ((const uchar4*)((const unsigned char*)smask + i))[0];
        const uchar4 b = ((const uchar4*)((const unsigned char*)smask + i))[1];
        mb[0]=a.x; mb[1]=a.y; mb[2]=a.z; mb[3]=a.w;
        mb[4]=b.x; mb[5]=b.y; mb[6]=b.z; mb[7]=b.w;
    } else {
        const int* p = (const int*)smask + i;
        #pragma unroll
        for (int j = 0; j < 8; ++j) mb[j] = p[j];
    }
}

// ---------------------------------------------------------------------------
// Weight prep: W[K][N] fp32 -> Wt[N][Kp] bf16 (zero-filled to Kp).
// ---------------------------------------------------------------------------
struct PDesc { const float* src; short* dst; int K, N, Kp, ntx, tiles; };
struct PArgs { PDesc d[8]; int nd; };

__global__ __launch_bounds__(256) void prep_kernel(PArgs pa)
{
    __shared__ short T[64][72];
    int tile = blockIdx.x, g = 0;
    while (g + 1 < pa.nd && tile >= pa.d[g].tiles) { tile -= pa.d[g].tiles; ++g; }
    const PDesc d = pa.d[g];
    const int kt = tile / d.ntx, nt = tile % d.ntx;
    const int k0 = kt * 64, n0 = nt * 64;
    const int tid = threadIdx.x;
    {
        const int n = n0 + (tid & 63);
        #pragma unroll
        for (int p = 0; p < 16; ++p) {
            const int kk = p * 4 + (tid >> 6);
            const int k = k0 + kk;
            float v = 0.f;
            if (k < d.K && n < d.N) v = d.src[(size_t)k * d.N + n];
            T[kk][tid & 63] = f2bf(v);
        }
    }
    __syncthreads();
    {
        const int kk = (tid & 31) * 2;
        #pragma unroll
        for (int p = 0; p < 8; ++p) {
            const int nn = p * 8 + (tid >> 5);
            const int n = n0 + nn;
            if (n >= d.N) continue;
            short2 s = { T[kk][nn], T[kk + 1][nn] };
            *(short2*)&d.dst[(size_t)n * d.Kp + k0 + kk] = s;
        }
    }
}

// ---------------------------------------------------------------------------
// Batched bf16-MFMA GEMM v4: C[M,N] = A[M,K]@B[K,N] (+bias); fp32 A,
// bf16 Wt[N][Kp] B; C fp32 or bf16 (obf). 128x128 tile, BK=32, dbuf LDS
// (row dim padded 130 -> conflict-free staging). obf path also computes
// per-(row, n-tile) masked softmax partials into pstat (fused stats).
// ---------------------------------------------------------------------------
struct GDesc { const float* A; const short* Bt; const float* bias; void* C;
               const void* smask; float* pstat;
               int M, N, K, Kp, nx, my, obf, nt, tiles; };
struct GArgs { GDesc d[7]; int nd; };

__global__ __launch_bounds__(256) void gemm_bf16_kernel(GArgs ga)
{
    __shared__ short As[2][4][130][8];
    __shared__ short Bs[2][4][130][8];
    __shared__ float pm_s[128][2];
    __shared__ float ps_s[128][2];

    int tile = blockIdx.x, g = 0;
    while (g + 1 < ga.nd && tile >= ga.d[g].tiles) { tile -= ga.d[g].tiles; ++g; }
    const float* __restrict__ A  = ga.d[g].A;
    const short* __restrict__ Bt = ga.d[g].Bt;
    const float* bias = ga.d[g].bias;
    const int N = ga.d[g].N, K = ga.d[g].K, Kp = ga.d[g].Kp;
    const int nx = ga.d[g].nx, my = ga.d[g].my, obf = ga.d[g].obf;

    int bm, bn;
    if (my > 0) { bm = (tile % my) * 128; bn = (tile / my) * 128; }
    else        { bm = (tile / nx) * 128; bn = (tile % nx) * 128; }
    const int tid  = threadIdx.x;
    const int lane = tid & 63;
    const int wv   = tid >> 6;
    const int wm   = (wv >> 1) * 64;
    const int wn   = (wv & 1) * 64;

    const int a_kq  = (tid & 7) * 4;
    const int a_row = tid >> 3;
    float4  ra[4];
    bf16x8  rb[2];

    auto loadA = [&](int k0) {
        #pragma unroll
        for (int p = 0; p < 4; ++p) {
            const int row = p * 32 + a_row;
            const int gk = k0 + a_kq;
            const float* ap = A + (size_t)(bm + row) * K + gk;
            float4 a = make_float4(0.f, 0.f, 0.f, 0.f);
            if (gk + 3 < K) a = *(const float4*)ap;
            else {
                if (gk     < K) a.x = ap[0];
                if (gk + 1 < K) a.y = ap[1];
                if (gk + 2 < K) a.z = ap[2];
                if (gk + 3 < K) a.w = ap[3];
            }
            ra[p] = a;
        }
    };
    auto loadB = [&](int k0) {
        #pragma unroll
        for (int p = 0; p < 2; ++p) {
            const int idx = p * 256 + tid;
            const int n = idx >> 2, kb = idx & 3;
            const int gn = bn + n;
            bf16x8 v = {};
            if (gn < N) v = *(const bf16x8*)&Bt[(size_t)gn * Kp + k0 + kb * 8];
            rb[p] = v;
        }
    };
    auto storeA = [&](int buf) {
        const int kb = a_kq >> 3, ko = a_kq & 7;
        #pragma unroll
        for (int p = 0; p < 4; ++p) {
            const int row = p * 32 + a_row;
            short4 s = { f2bf(ra[p].x), f2bf(ra[p].y), f2bf(ra[p].z), f2bf(ra[p].w) };
            *(short4*)&As[buf][kb][row][ko] = s;
        }
    };
    auto storeB = [&](int buf) {
        #pragma unroll
        for (int p = 0; p < 2; ++p) {
            const int idx = p * 256 + tid;
            const int n = idx >> 2, kb = idx & 3;
            *(bf16x8*)&Bs[buf][kb][n][0] = rb[p];
        }
    };

    f32x4 acc[4][4] = {};
    const int nk = Kp / 32;

    loadA(0); loadB(0);
    storeA(0); storeB(0);
    __syncthreads();

    for (int kk = 0; kk < nk; ++kk) {
        const int cur = kk & 1;
        if (kk + 1 < nk) { loadA((kk + 1) * 32); loadB((kk + 1) * 32); }
        bf16x8 af[4], bfr[4];
        #pragma unroll
        for (int i = 0; i < 4; ++i) {
            af[i]  = *(const bf16x8*)&As[cur][lane >> 4][wm + i * 16 + (lane & 15)][0];
            bfr[i] = *(const bf16x8*)&Bs[cur][lane >> 4][wn + i * 16 + (lane & 15)][0];
        }
        #pragma unroll
        for (int mi = 0; mi < 4; ++mi)
            #pragma unroll
            for (int ni = 0; ni < 4; ++ni)
                acc[mi][ni] = __builtin_amdgcn_mfma_f32_16x16x32_bf16(
                    af[mi], bfr[ni], acc[mi][ni], 0, 0, 0);
        if (kk + 1 < nk) { storeA(cur ^ 1); storeB(cur ^ 1); }
        __syncthreads();
    }

    if (!obf) {
        float* Cf = (float*)ga.d[g].C;
        #pragma unroll
        for (int ni = 0; ni < 4; ++ni) {
            const int gn = bn + wn + ni * 16 + (lane & 15);
            if (gn >= N) continue;
            const float bb = bias ? bias[gn] : 0.f;
            #pragma unroll
            for (int mi = 0; mi < 4; ++mi)
                #pragma unroll
                for (int r = 0; r < 4; ++r) {
                    const int gm = bm + wm + mi * 16 + (lane >> 4) * 4 + r;
                    Cf[(size_t)gm * N + gn] = acc[mi][ni][r] + bb;
                }
        }
    } else {
        // bf16 C write + fused masked softmax partials (no bias on this path)
        short* Cs = (short*)ga.d[g].C;
        const void* sm = ga.d[g].smask;
        const bool byteLayout = (((const int*)sm)[1] == 0x01010101);
        int mk[4];
        #pragma unroll
        for (int ni = 0; ni < 4; ++ni) {
            const int gn = bn + wn + ni * 16 + (lane & 15);
            const bool inb = (gn < N);
            mk[ni] = inb && smask_true(sm, byteLayout, inb ? gn : 0);
            if (inb) {
                #pragma unroll
                for (int mi = 0; mi < 4; ++mi)
                    #pragma unroll
                    for (int r = 0; r < 4; ++r) {
                        const int gm = bm + wm + mi * 16 + (lane >> 4) * 4 + r;
                        Cs[(size_t)gm * N + gn] = f2bf(acc[mi][ni][r]);
                    }
            }
        }
        #pragma unroll
        for (int mi = 0; mi < 4; ++mi) {
            #pragma unroll
            for (int r = 0; r < 4; ++r) {
                const int rl = wm + mi * 16 + (lane >> 4) * 4 + r;  // 0..127
                float vmax = -INFINITY;
                #pragma unroll
                for (int ni = 0; ni < 4; ++ni)
                    if (mk[ni]) vmax = fmaxf(vmax, acc[mi][ni][r]);
                #pragma unroll
                for (int o = 1; o < 16; o <<= 1)
                    vmax = fmaxf(vmax, __shfl_xor(vmax, o));
                float se = 0.f;
                #pragma unroll
                for (int ni = 0; ni < 4; ++ni)
                    if (mk[ni]) se += __expf(acc[mi][ni][r] - vmax);
                #pragma unroll
                for (int o = 1; o < 16; o <<= 1)
                    se += __shfl_xor(se, o);
                if ((lane & 15) == 0) {
                    pm_s[rl][wn >> 6] = vmax;
                    ps_s[rl][wn >> 6] = se;
                }
            }
        }
        __syncthreads();
        if (tid < 128) {
            const float mA = pm_s[tid][0], mB = pm_s[tid][1];
            const float sA = ps_s[tid][0], sB = ps_s[tid][1];
            const float m = fmaxf(mA, mB);
            float s = 0.f;
            if (sA > 0.f) s += sA * __expf(mA - m);
            if (sB > 0.f) s += sB * __expf(mB - m);
            float* ps = ga.d[g].pstat;
            const size_t idx = ((size_t)(bm + tid) * ga.d[g].nt + (bn >> 7)) * 2;
            ps[idx + 0] = m;
            ps[idx + 1] = s;
        }
    }
}

// ---------------------------------------------------------------------------
// Merged scores + softmax + ctx + mixture: one block (512 thr) per (b,t).
// 8 waves score 336/8=42 keys each (uniform branch per wave-iteration).
// ---------------------------------------------------------------------------
__global__ __launch_bounds__(512) void scoremix_kernel(
    const float* __restrict__ KpQ, const float* __restrict__ KpA,
    const float* __restrict__ KpP,
    const float* __restrict__ QpQ, const float* __restrict__ QpA,
    const float* __restrict__ QpP,
    const float* __restrict__ v_q, const float* __restrict__ v_a,
    const float* __restrict__ v_p,
    const float* __restrict__ Mq, const float* __restrict__ Mqa,
    const float* __restrict__ Mp, const float* __restrict__ Mnlg,
    const float* __restrict__ Wm, const float* __restrict__ bm,
    float* __restrict__ dQ, float* __restrict__ dQA, float* __restrict__ dP,
    float* __restrict__ lam_ws, float* __restrict__ lam_out)
{
    __shared__ float sc[SRC_TOT];
    __shared__ float a_sh[SRC_TOT];
    __shared__ float cQ[DM], cA[DM], cP[DM];
    __shared__ float red[16];
    __shared__ float redm[32];
    const int bt   = blockIdx.x;
    const int b    = bt / TT;
    const int tid  = threadIdx.x;
    const int lane = tid & 63;
    const int wave = tid >> 6;          // 0..7

    float qpQ[8], qpA[8], qpP[8], vvQ[8], vvA[8], vvP[8];
    {
        auto ld8 = [&](float (&dst)[8], const float* p) {
            const float4 a = ((const float4*)p)[0];
            const float4 c = ((const float4*)p)[1];
            dst[0]=a.x; dst[1]=a.y; dst[2]=a.z; dst[3]=a.w;
            dst[4]=c.x; dst[5]=c.y; dst[6]=c.z; dst[7]=c.w;
        };
        ld8(qpQ, QpQ + (size_t)bt * DM + lane * 8);
        ld8(qpA, QpA + (size_t)bt * DM + lane * 8);
        ld8(qpP, QpP + (size_t)bt * DM + lane * 8);
        ld8(vvQ, v_q + lane * 8);
        ld8(vvA, v_a + lane * 8);
        ld8(vvP, v_p + lane * 8);
    }
    auto dot = [&](const float* krow, const float (&qp)[8], const float (&vv)[8]) {
        const float4 ka = ((const float4*)(krow + lane * 8))[0];
        const float4 kb = ((const float4*)(krow + lane * 8))[1];
        float acc = 0.f;
        acc = fmaf(vv[0], fast_tanh(qp[0] + ka.x), acc);
        acc = fmaf(vv[1], fast_tanh(qp[1] + ka.y), acc);
        acc = fmaf(vv[2], fast_tanh(qp[2] + ka.z), acc);
        acc = fmaf(vv[3], fast_tanh(qp[3] + ka.w), acc);
        acc = fmaf(vv[4], fast_tanh(qp[4] + kb.x), acc);
        acc = fmaf(vv[5], fast_tanh(qp[5] + kb.y), acc);
        acc = fmaf(vv[6], fast_tanh(qp[6] + kb.z), acc);
        acc = fmaf(vv[7], fast_tanh(qp[7] + kb.w), acc);
        return acc;
    };
    for (int s = wave; s < SRC_TOT; s += 8) {
        float acc;
        if (s < JJ)
            acc = dot(KpQ + ((size_t)b * JJ + s) * DM, qpQ, vvQ);
        else if (s < JJ + NN)
            acc = dot(KpA + ((size_t)b * NN + (s - JJ)) * DM, qpA, vvA);
        else
            acc = dot(KpP + ((size_t)b * LL + (s - JJ - NN)) * DM, qpP, vvP);
        #pragma unroll
        for (int o = 32; o; o >>= 1) acc += __shfl_xor(acc, o);
        if (lane == 0) sc[s] = acc;
    }
    __syncthreads();

    #pragma unroll
    for (int br = 0; br < 3; ++br) {
        const int off = (br == 0) ? 0 : (br == 1) ? JJ : (JJ + NN);
        const int cnt = (br == 0) ? JJ : (br == 1) ? NN : LL;
        float x = (tid < cnt) ? sc[off + tid] : -INFINITY;
        float m = x;
        #pragma unroll
        for (int o = 32; o; o >>= 1) m = fmaxf(m, __shfl_xor(m, o));
        if (lane == 0) red[wave] = m;
        __syncthreads();
        m = red[0];
        #pragma unroll
        for (int w = 1; w < 8; ++w) m = fmaxf(m, red[w]);
        float e = (tid < cnt) ? __expf(x - m) : 0.f;
        float ss = e;
        #pragma unroll
        for (int o = 32; o; o >>= 1) ss += __shfl_xor(ss, o);
        if (lane == 0) red[8 + wave] = ss;
        __syncthreads();
        float denom = 0.f;
        #pragma unroll
        for (int w = 0; w < 8; ++w) denom += red[8 + w];
        if (tid < cnt) {
            const float a = e / denom;
            a_sh[off + tid] = a;
            float* dst = (br == 0) ? dQ : (br == 1) ? dQA : dP;
            dst[(size_t)bt * cnt + tid] = a;
        }
        __syncthreads();
    }
    // ctx for d = tid (0..511), kept in LDS
    {
        float aQ = 0.f, aA = 0.f, aP = 0.f;
        for (int s = 0; s < JJ; ++s)
            aQ = fmaf(a_sh[s],           Mq [((size_t)b * JJ + s) * DM + tid], aQ);
        for (int s = 0; s < NN; ++s)
            aA = fmaf(a_sh[JJ + s],      Mqa[((size_t)b * NN + s) * DM + tid], aA);
        for (int s = 0; s < LL; ++s)
            aP = fmaf(a_sh[JJ + NN + s], Mp [((size_t)b * LL + s) * DM + tid], aP);
        cQ[tid] = aQ; cA[tid] = aA; cP[tid] = aP;
    }
    __syncthreads();
    // mix: thread handles k = tid, tid+512, tid+1024, tid+1536
    {
        const float x0 = Mnlg[(size_t)bt * DM + tid];
        const float x1 = cQ[tid], x2 = cA[tid], x3 = cP[tid];
        const float4 w0 = *(const float4*)&Wm[(size_t)tid * 4];
        const float4 w1 = *(const float4*)&Wm[(size_t)(512 + tid) * 4];
        const float4 w2 = *(const float4*)&Wm[(size_t)(1024 + tid) * 4];
        const float4 w3 = *(const float4*)&Wm[(size_t)(1536 + tid) * 4];
        float acc[4];
        acc[0] = x0 * w0.x + x1 * w1.x + x2 * w2.x + x3 * w3.x;
        acc[1] = x0 * w0.y + x1 * w1.y + x2 * w2.y + x3 * w3.y;
        acc[2] = x0 * w0.z + x1 * w1.z + x2 * w2.z + x3 * w3.z;
        acc[3] = x0 * w0.w + x1 * w1.w + x2 * w2.w + x3 * w3.w;
        #pragma unroll
        for (int c = 0; c < 4; ++c)
            #pragma unroll
            for (int o = 32; o; o >>= 1) acc[c] += __shfl_xor(acc[c], o);
        if (lane == 0) {
            redm[wave * 4 + 0] = acc[0]; redm[wave * 4 + 1] = acc[1];
            redm[wave * 4 + 2] = acc[2]; redm[wave * 4 + 3] = acc[3];
        }
        __syncthreads();
        if (tid == 0) {
            float l[4];
            #pragma unroll
            for (int c = 0; c < 4; ++c) {
                float s = bm[c];
                #pragma unroll
                for (int w = 0; w < 8; ++w) s += redm[w * 4 + c];
                l[c] = s;
            }
            const float mx = fmaxf(fmaxf(l[0], l[1]), fmaxf(l[2], l[3]));
            const float e0 = __expf(l[0] - mx), e1 = __expf(l[1] - mx);
            const float e2 = __expf(l[2] - mx), e3 = __expf(l[3] - mx);
            const float inv = 1.f / (e0 + e1 + e2 + e3);
            lam_ws[bt * 4 + 0] = e0 * inv; lam_out[bt * 4 + 0] = e0 * inv;
            lam_ws[bt * 4 + 1] = e1 * inv; lam_out[bt * 4 + 1] = e1 * inv;
            lam_ws[bt * 4 + 2] = e2 * inv; lam_out[bt * 4 + 2] = e2 * inv;
            lam_ws[bt * 4 + 3] = e3 * inv; lam_out[bt * 4 + 3] = e3 * inv;
        }
    }
}

// ---------------------------------------------------------------------------
// Merged row write + scatter: one block (1024 thr) per row.
// Combines the NT per-tile softmax partials (uniform per block), writes the
// full 32000-wide row (bf16 logits -> fp32 probs, zero tail), then scatters
// the 336 source entries after an intra-block barrier.
// ---------------------------------------------------------------------------
__global__ __launch_bounds__(1024) void writescatter_kernel(
    const short* __restrict__ logits, const void* __restrict__ smask,
    const float* __restrict__ pstat, const float* __restrict__ lam,
    const float* __restrict__ dP, const float* __restrict__ dQ,
    const float* __restrict__ dQA, const void* __restrict__ src_ext,
    float* __restrict__ out)
{
    const bool byteLayout = (((const int*)smask)[1] == 0x01010101);
    const int r = blockIdx.x;
    float m = -INFINITY;
    for (int c = 0; c < NT; ++c) m = fmaxf(m, pstat[((size_t)r * NT + c) * 2]);
    float dsum = 0.f;
    for (int c = 0; c < NT; ++c) {
        const float pm = pstat[((size_t)r * NT + c) * 2];
        const float ps = pstat[((size_t)r * NT + c) * 2 + 1];
        if (ps > 0.f) dsum += ps * __expf(pm - m);
    }
    const float inv = lam[r * 4 + 0] / dsum;

    const short* lrow = logits + (size_t)r * DFIX;
    float* orow = out + (size_t)r * DEXT;
    const int tid = threadIdx.x;
    #pragma unroll
    for (int k = 0; k < 4; ++k) {
        const int i = (k * 1024 + tid) * 8;
        if (i >= DEXT) continue;
        float4 o0 = make_float4(0.f, 0.f, 0.f, 0.f);
        float4 o1 = make_float4(0.f, 0.f, 0.f, 0.f);
        if (i < DFIX) {                 // 30000 % 8 == 0: no straddle
            const bf16x8 v = *(const bf16x8*)&lrow[i];
            int mb[8]; mask8(smask, byteLayout, i, mb);
            o0.x = mb[0] ? __expf(bf2f(v[0]) - m) * inv : 0.f;
            o0.y = mb[1] ? __expf(bf2f(v[1]) - m) * inv : 0.f;
            o0.z = mb[2] ? __expf(bf2f(v[2]) - m) * inv : 0.f;
            o0.w = mb[3] ? __expf(bf2f(v[3]) - m) * inv : 0.f;
            o1.x = mb[4] ? __expf(bf2f(v[4]) - m) * inv : 0.f;
            o1.y = mb[5] ? __expf(bf2f(v[5]) - m) * inv : 0.f;
            o1.z = mb[6] ? __expf(bf2f(v[6]) - m) * inv : 0.f;
            o1.w = mb[7] ? __expf(bf2f(v[7]) - m) * inv : 0.f;
        }
        *(float4*)&orow[i]     = o0;
        *(float4*)&orow[i + 4] = o1;
    }
    __syncthreads();
    if (tid < SRC_TOT) {
        const int* s32 = (const int*)src_ext;
        const bool src64 = (s32[1] == 0 && s32[3] == 0 && s32[5] == 0 && s32[7] == 0);
        const int b = r / TT;
        const float lamq  = lam[r * 4 + 1];
        const float lamqa = lam[r * 4 + 2];
        const float lamp  = lam[r * 4 + 3];
        const int pos = b * SRC_TOT + tid;
        const int idx = src64 ? (int)((const long long*)src_ext)[pos] : s32[pos];
        float val;
        if      (tid < LL)      val = dP [(size_t)r * LL + tid]             * lamp;
        else if (tid < LL + JJ) val = dQ [(size_t)r * JJ + (tid - LL)]      * lamq;
        else                    val = dQA[(size_t)r * NN + (tid - LL - JJ)] * lamqa;
        atomicAdd(&orow[idx], val);
    }
}

// ---------------------------------------------------------------------------
extern "C" void kernel_launch(void* const* d_in, const int* in_sizes, int n_in,
                              void* d_out, int out_size, void* d_ws, size_t ws_size,
                              hipStream_t stream)
{
    const float* Mp   = (const float*)d_in[0];
    const float* Mq   = (const float*)d_in[1];
    const float* Mqa  = (const float*)d_in[2];
    const float* Mnlg = (const float*)d_in[3];
    const void* src_ext = d_in[7];
    const void* smask   = d_in[8];
    const float* Wk_q = (const float*)d_in[10];
    const float* bk_q = (const float*)d_in[11];
    const float* Wq_q = (const float*)d_in[12];
    const float* bq_q = (const float*)d_in[13];
    const float* v_q  = (const float*)d_in[14];
    const float* Wk_a = (const float*)d_in[15];
    const float* bk_a = (const float*)d_in[16];
    const float* Wq_a = (const float*)d_in[17];
    const float* bq_a = (const float*)d_in[18];
    const float* v_a  = (const float*)d_in[19];
    const float* Wk_p = (const float*)d_in[20];
    const float* bk_p = (const float*)d_in[21];
    const float* Wq_p = (const float*)d_in[22];
    const float* bq_p = (const float*)d_in[23];
    const float* v_p  = (const float*)d_in[24];
    const float* W1   = (const float*)d_in[25];
    const float* b1   = (const float*)d_in[26];
    const float* W2   = (const float*)d_in[27];
    const float* Wm   = (const float*)d_in[28];
    const float* bm   = (const float*)d_in[29];
    float* out = (float*)d_out;

    char* ws = (char*)d_ws;
    size_t off = 0;
    auto alloc = [&](size_t bytes) -> char* {
        char* p = ws + off;
        off += (bytes + 255) & ~(size_t)255;
        return p;
    };
    short* logits = (short*)alloc((size_t)ROWS * DFIX * 2);   // bf16
    float* KpP    = (float*)alloc((size_t)BS * LL * DM * 4);
    float* KpQ    = (float*)alloc((size_t)BS * JJ * DM * 4);
    float* KpA    = (float*)alloc((size_t)BS * NN * DM * 4);
    float* QpQ    = (float*)alloc((size_t)ROWS * DM * 4);
    float* QpA    = (float*)alloc((size_t)ROWS * DM * 4);
    float* QpP    = (float*)alloc((size_t)ROWS * DM * 4);
    float* Hh     = (float*)alloc((size_t)ROWS * DEMB * 4);
    float* dP     = (float*)alloc((size_t)ROWS * LL * 4);
    float* dQ     = (float*)alloc((size_t)ROWS * JJ * 4);
    float* dQA    = (float*)alloc((size_t)ROWS * NN * 4);
    float* lam    = (float*)alloc((size_t)ROWS * 4 * 4);
    float* pstat  = (float*)alloc((size_t)ROWS * NT * 2 * 4);
    short* tWkq = (short*)alloc((size_t)DM * DM * 2);
    short* tWqq = (short*)alloc((size_t)DM * DM * 2);
    short* tWka = (short*)alloc((size_t)DM * DM * 2);
    short* tWqa = (short*)alloc((size_t)DM * DM * 2);
    short* tWkp = (short*)alloc((size_t)DM * DM * 2);
    short* tWqp = (short*)alloc((size_t)DM * DM * 2);
    short* tW1  = (short*)alloc((size_t)DEMB * DM * 2);
    short* tW2  = (short*)alloc((size_t)DFIX * 320 * 2);
    (void)ws_size; (void)in_sizes; (void)n_in; (void)out_size;

    // ---- prep: transpose+cast weights
    PArgs pa;
    pa.nd = 8;
    pa.d[0] = { Wk_p, tWkp, DM,   DM,   DM,  8,  64 };
    pa.d[1] = { Wk_q, tWkq, DM,   DM,   DM,  8,  64 };
    pa.d[2] = { Wk_a, tWka, DM,   DM,   DM,  8,  64 };
    pa.d[3] = { Wq_q, tWqq, DM,   DM,   DM,  8,  64 };
    pa.d[4] = { Wq_a, tWqa, DM,   DM,   DM,  8,  64 };
    pa.d[5] = { Wq_p, tWqp, DM,   DM,   DM,  8,  64 };
    pa.d[6] = { W1,   tW1,  DM,   DEMB, DM,  5,  40 };
    pa.d[7] = { W2,   tW2,  DEMB, DFIX, 320, 469, 2345 };
    prep_kernel<<<64 * 6 + 40 + 2345, 256, 0, stream>>>(pa);

    // ---- launch A: Hh = Mnlg @ W1 + b1
    GArgs gA;
    gA.nd = 1;
    gA.d[0] = { Mnlg, tW1, b1, Hh, nullptr, nullptr,
                ROWS, DEMB, DM, DM, 3, 0, 0, 0, 9 };
    gemm_bf16_kernel<<<9, 256, 0, stream>>>(gA);

    // ---- launch B: projections (long-K) FIRST, logits (short-K) last.
    GArgs gB;
    gB.nd = 7;
    gB.d[0] = { Mp,   tWkp, bk_p,    KpP,    nullptr, nullptr,
                BS*LL, DM,   DM,   DM,  4,   0, 0, 0,  64 };
    gB.d[1] = { Mq,   tWkq, bk_q,    KpQ,    nullptr, nullptr,
                BS*JJ, DM,   DM,   DM,  4,   0, 0, 0,  12 };
    gB.d[2] = { Mqa,  tWka, bk_a,    KpA,    nullptr, nullptr,
                BS*NN, DM,   DM,   DM,  4,   0, 0, 0,   8 };
    gB.d[3] = { Mnlg, tWqq, bq_q,    QpQ,    nullptr, nullptr,
                ROWS,  DM,   DM,   DM,  4,   0, 0, 0,  12 };
    gB.d[4] = { Mnlg, tWqa, bq_a,    QpA,    nullptr, nullptr,
                ROWS,  DM,   DM,   DM,  4,   0, 0, 0,  12 };
    gB.d[5] = { Mnlg, tWqp, bq_p,    QpP,    nullptr, nullptr,
                ROWS,  DM,   DM,   DM,  4,   0, 0, 0,  12 };
    gB.d[6] = { Hh,   tW2,  nullptr, logits, smask,   pstat,
                ROWS,  DFIX, DEMB, 320, 235, 3, 1, NT, 705 };
    gemm_bf16_kernel<<<825, 256, 0, stream>>>(gB);

    // ---- merged scores + softmax + ctx + mixture
    scoremix_kernel<<<ROWS, 512, 0, stream>>>(
        KpQ, KpA, KpP, QpQ, QpA, QpP, v_q, v_a, v_p,
        Mq, Mqa, Mp, Mnlg, Wm, bm, dQ, dQA, dP,
        lam, out + (size_t)ROWS * DEXT);

    // ---- merged row write + scatter
    writescatter_kernel<<<ROWS, 1024, 0, stream>>>(
        logits, smask, pstat, lam, dP, dQ, dQA, src_ext, out);
}

// Round 11
// 218.053 us; speedup vs baseline: 1.1706x; 1.1706x over previous
//
#include <hip/hip_runtime.h>
#include <math.h>

// ---------------------------------------------------------------------------
// Problem constants
// ---------------------------------------------------------------------------
#define BS     8
#define LL     256
#define JJ     48
#define NN     32
#define TT     48
#define DM     512
#define DEMB   300
#define DFIX   30000
#define DEXT   32000
#define SRC_TOT (LL + JJ + NN)      // 336
#define ROWS   (BS * TT)            // 384
#define NT     235                  // logits n-tiles (235*128 = 30080)

typedef float f32x4  __attribute__((ext_vector_type(4)));
typedef short bf16x8 __attribute__((ext_vector_type(8)));

__device__ __forceinline__ short f2bf(float f) {
    union { float f; unsigned u; } v; v.f = f;
    return (short)((v.u + 0x7FFFu + ((v.u >> 16) & 1u)) >> 16);  // RNE
}
__device__ __forceinline__ float bf2f(short s) {
    union { unsigned u; float f; } v;
    v.u = ((unsigned)(unsigned short)s) << 16;
    return v.f;
}
__device__ __forceinline__ float fast_exp2(float x) {
#if __has_builtin(__builtin_amdgcn_exp2f)
    return __builtin_amdgcn_exp2f(x);
#else
    return exp2f(x);
#endif
}
__device__ __forceinline__ float fast_rcp(float x) {
#if __has_builtin(__builtin_amdgcn_rcpf)
    return __builtin_amdgcn_rcpf(x);
#else
    return 1.f / x;
#endif
}
__device__ __forceinline__ float fast_tanh(float x) {
    x = fminf(fmaxf(x, -15.f), 15.f);
    const float e = fast_exp2(x * 2.885390082f);
    return (e - 1.f) * fast_rcp(e + 1.f);
}
__device__ __forceinline__ bool smask_true(const void* smask, bool byteLayout, int i)
{
    if (byteLayout) return ((const unsigned char*)smask)[i] != 0;
    return ((const int*)smask)[i] != 0;
}
__device__ __forceinline__ void mask8(const void* smask, bool byteLayout, int i,
                                      int* mb)
{
    if (byteLayout) {
        const uchar4 a = ((const uchar4*)((const unsigned char*)smask + i))[0];
        const uchar4 b = ((const uchar4*)((const unsigned char*)smask + i))[1];
        mb[0]=a.x; mb[1]=a.y; mb[2]=a.z; mb[3]=a.w;
        mb[4]=b.x; mb[5]=b.y; mb[6]=b.z; mb[7]=b.w;
    } else {
        const int* p = (const int*)smask + i;
        #pragma unroll
        for (int j = 0; j < 8; ++j) mb[j] = p[j];
    }
}

// ---------------------------------------------------------------------------
// Weight prep: W[K][N] fp32 -> Wt[N][Kp] bf16 (zero-filled to Kp).
// Write phase: thread owns (row, 16-elem k-chunk) -> 2x contiguous 16B
// stores; 4-thread groups cover 128B contiguous (coalesced).
// ---------------------------------------------------------------------------
struct PDesc { const float* src; short* dst; int K, N, Kp, ntx, tiles; };
struct PArgs { PDesc d[8]; int nd; };

__global__ __launch_bounds__(256) void prep_kernel(PArgs pa)
{
    __shared__ short T[64][72];
    int tile = blockIdx.x, g = 0;
    while (g + 1 < pa.nd && tile >= pa.d[g].tiles) { tile -= pa.d[g].tiles; ++g; }
    const PDesc d = pa.d[g];
    const int kt = tile / d.ntx, nt = tile % d.ntx;
    const int k0 = kt * 64, n0 = nt * 64;
    const int tid = threadIdx.x;
    {
        const int n = n0 + (tid & 63);
        #pragma unroll
        for (int p = 0; p < 16; ++p) {
            const int kk = p * 4 + (tid >> 6);
            const int k = k0 + kk;
            float v = 0.f;
            if (k < d.K && n < d.N) v = d.src[(size_t)k * d.N + n];
            T[kk][tid & 63] = f2bf(v);
        }
    }
    __syncthreads();
    {
        const int nn = tid >> 2;          // 0..63
        const int kq = (tid & 3) * 16;    // 0,16,32,48
        const int n = n0 + nn;
        if (n < d.N) {
            bf16x8 v0, v1;
            #pragma unroll
            for (int j = 0; j < 8; ++j) v0[j] = T[kq + j][nn];
            #pragma unroll
            for (int j = 0; j < 8; ++j) v1[j] = T[kq + 8 + j][nn];
            *(bf16x8*)&d.dst[(size_t)n * d.Kp + k0 + kq]     = v0;
            *(bf16x8*)&d.dst[(size_t)n * d.Kp + k0 + kq + 8] = v1;
        }
    }
}

// ---------------------------------------------------------------------------
// Batched bf16-MFMA GEMM v4: C[M,N] = A[M,K]@B[K,N] (+bias); fp32 A,
// bf16 Wt[N][Kp] B; C fp32 or bf16 (obf). 128x128 tile, BK=32, dbuf LDS
// (row dim padded 130 -> conflict-free staging). obf path also computes
// per-(row, n-tile) masked softmax partials into pstat (fused stats).
// ---------------------------------------------------------------------------
struct GDesc { const float* A; const short* Bt; const float* bias; void* C;
               const void* smask; float* pstat;
               int M, N, K, Kp, nx, my, obf, nt, tiles; };
struct GArgs { GDesc d[7]; int nd; };

__global__ __launch_bounds__(256) void gemm_bf16_kernel(GArgs ga)
{
    __shared__ short As[2][4][130][8];
    __shared__ short Bs[2][4][130][8];
    __shared__ float pm_s[128][2];
    __shared__ float ps_s[128][2];

    int tile = blockIdx.x, g = 0;
    while (g + 1 < ga.nd && tile >= ga.d[g].tiles) { tile -= ga.d[g].tiles; ++g; }
    const float* __restrict__ A  = ga.d[g].A;
    const short* __restrict__ Bt = ga.d[g].Bt;
    const float* bias = ga.d[g].bias;
    const int N = ga.d[g].N, K = ga.d[g].K, Kp = ga.d[g].Kp;
    const int nx = ga.d[g].nx, my = ga.d[g].my, obf = ga.d[g].obf;

    int bm, bn;
    if (my > 0) { bm = (tile % my) * 128; bn = (tile / my) * 128; }
    else        { bm = (tile / nx) * 128; bn = (tile % nx) * 128; }
    const int tid  = threadIdx.x;
    const int lane = tid & 63;
    const int wv   = tid >> 6;
    const int wm   = (wv >> 1) * 64;
    const int wn   = (wv & 1) * 64;

    const int a_kq  = (tid & 7) * 4;
    const int a_row = tid >> 3;
    float4  ra[4];
    bf16x8  rb[2];

    auto loadA = [&](int k0) {
        #pragma unroll
        for (int p = 0; p < 4; ++p) {
            const int row = p * 32 + a_row;
            const int gk = k0 + a_kq;
            const float* ap = A + (size_t)(bm + row) * K + gk;
            float4 a = make_float4(0.f, 0.f, 0.f, 0.f);
            if (gk + 3 < K) a = *(const float4*)ap;
            else {
                if (gk     < K) a.x = ap[0];
                if (gk + 1 < K) a.y = ap[1];
                if (gk + 2 < K) a.z = ap[2];
                if (gk + 3 < K) a.w = ap[3];
            }
            ra[p] = a;
        }
    };
    auto loadB = [&](int k0) {
        #pragma unroll
        for (int p = 0; p < 2; ++p) {
            const int idx = p * 256 + tid;
            const int n = idx >> 2, kb = idx & 3;
            const int gn = bn + n;
            bf16x8 v = {};
            if (gn < N) v = *(const bf16x8*)&Bt[(size_t)gn * Kp + k0 + kb * 8];
            rb[p] = v;
        }
    };
    auto storeA = [&](int buf) {
        const int kb = a_kq >> 3, ko = a_kq & 7;
        #pragma unroll
        for (int p = 0; p < 4; ++p) {
            const int row = p * 32 + a_row;
            short4 s = { f2bf(ra[p].x), f2bf(ra[p].y), f2bf(ra[p].z), f2bf(ra[p].w) };
            *(short4*)&As[buf][kb][row][ko] = s;
        }
    };
    auto storeB = [&](int buf) {
        #pragma unroll
        for (int p = 0; p < 2; ++p) {
            const int idx = p * 256 + tid;
            const int n = idx >> 2, kb = idx & 3;
            *(bf16x8*)&Bs[buf][kb][n][0] = rb[p];
        }
    };

    f32x4 acc[4][4] = {};
    const int nk = Kp / 32;

    loadA(0); loadB(0);
    storeA(0); storeB(0);
    __syncthreads();

    for (int kk = 0; kk < nk; ++kk) {
        const int cur = kk & 1;
        if (kk + 1 < nk) { loadA((kk + 1) * 32); loadB((kk + 1) * 32); }
        bf16x8 af[4], bfr[4];
        #pragma unroll
        for (int i = 0; i < 4; ++i) {
            af[i]  = *(const bf16x8*)&As[cur][lane >> 4][wm + i * 16 + (lane & 15)][0];
            bfr[i] = *(const bf16x8*)&Bs[cur][lane >> 4][wn + i * 16 + (lane & 15)][0];
        }
        #pragma unroll
        for (int mi = 0; mi < 4; ++mi)
            #pragma unroll
            for (int ni = 0; ni < 4; ++ni)
                acc[mi][ni] = __builtin_amdgcn_mfma_f32_16x16x32_bf16(
                    af[mi], bfr[ni], acc[mi][ni], 0, 0, 0);
        if (kk + 1 < nk) { storeA(cur ^ 1); storeB(cur ^ 1); }
        __syncthreads();
    }

    if (!obf) {
        float* Cf = (float*)ga.d[g].C;
        #pragma unroll
        for (int ni = 0; ni < 4; ++ni) {
            const int gn = bn + wn + ni * 16 + (lane & 15);
            if (gn >= N) continue;
            const float bb = bias ? bias[gn] : 0.f;
            #pragma unroll
            for (int mi = 0; mi < 4; ++mi)
                #pragma unroll
                for (int r = 0; r < 4; ++r) {
                    const int gm = bm + wm + mi * 16 + (lane >> 4) * 4 + r;
                    Cf[(size_t)gm * N + gn] = acc[mi][ni][r] + bb;
                }
        }
    } else {
        // bf16 C write + fused masked softmax partials (no bias on this path)
        short* Cs = (short*)ga.d[g].C;
        const void* sm = ga.d[g].smask;
        const bool byteLayout = (((const int*)sm)[1] == 0x01010101);
        int mk[4];
        #pragma unroll
        for (int ni = 0; ni < 4; ++ni) {
            const int gn = bn + wn + ni * 16 + (lane & 15);
            const bool inb = (gn < N);
            mk[ni] = inb && smask_true(sm, byteLayout, inb ? gn : 0);
            if (inb) {
                #pragma unroll
                for (int mi = 0; mi < 4; ++mi)
                    #pragma unroll
                    for (int r = 0; r < 4; ++r) {
                        const int gm = bm + wm + mi * 16 + (lane >> 4) * 4 + r;
                        Cs[(size_t)gm * N + gn] = f2bf(acc[mi][ni][r]);
                    }
            }
        }
        #pragma unroll
        for (int mi = 0; mi < 4; ++mi) {
            #pragma unroll
            for (int r = 0; r < 4; ++r) {
                const int rl = wm + mi * 16 + (lane >> 4) * 4 + r;  // 0..127
                float vmax = -INFINITY;
                #pragma unroll
                for (int ni = 0; ni < 4; ++ni)
                    if (mk[ni]) vmax = fmaxf(vmax, acc[mi][ni][r]);
                #pragma unroll
                for (int o = 1; o < 16; o <<= 1)
                    vmax = fmaxf(vmax, __shfl_xor(vmax, o));
                float se = 0.f;
                #pragma unroll
                for (int ni = 0; ni < 4; ++ni)
                    if (mk[ni]) se += __expf(acc[mi][ni][r] - vmax);
                #pragma unroll
                for (int o = 1; o < 16; o <<= 1)
                    se += __shfl_xor(se, o);
                if ((lane & 15) == 0) {
                    pm_s[rl][wn >> 6] = vmax;
                    ps_s[rl][wn >> 6] = se;
                }
            }
        }
        __syncthreads();
        if (tid < 128) {
            const float mA = pm_s[tid][0], mB = pm_s[tid][1];
            const float sA = ps_s[tid][0], sB = ps_s[tid][1];
            const float m = fmaxf(mA, mB);
            float s = 0.f;
            if (sA > 0.f) s += sA * __expf(mA - m);
            if (sB > 0.f) s += sB * __expf(mB - m);
            float* ps = ga.d[g].pstat;
            const size_t idx = ((size_t)(bm + tid) * ga.d[g].nt + (bn >> 7)) * 2;
            ps[idx + 0] = m;
            ps[idx + 1] = s;
        }
    }
}

// ---------------------------------------------------------------------------
// Attention scores, load-balanced: grid (ROWS, 6 chunks), 256 threads.
// ---------------------------------------------------------------------------
struct SDesc { const float* Kp; const float* Qp; const float* vv;
               int Sb, s0, cnt, off; };
struct SArgs { SDesc c[6]; };

__global__ __launch_bounds__(256) void scores_kernel(SArgs sa,
                                                     float* __restrict__ scb)
{
    const SDesc d = sa.c[blockIdx.y];
    const int bt   = blockIdx.x;
    const int b    = bt / TT;
    const int tid  = threadIdx.x;
    const int lane = tid & 63;
    const int wave = tid >> 6;

    float qp[8], vv[8];
    {
        const float4* q4 = (const float4*)(d.Qp + (size_t)bt * DM) + lane * 2;
        float4 a = q4[0], c = q4[1];
        qp[0]=a.x; qp[1]=a.y; qp[2]=a.z; qp[3]=a.w;
        qp[4]=c.x; qp[5]=c.y; qp[6]=c.z; qp[7]=c.w;
        const float4* v4 = (const float4*)d.vv + lane * 2;
        a = v4[0]; c = v4[1];
        vv[0]=a.x; vv[1]=a.y; vv[2]=a.z; vv[3]=a.w;
        vv[4]=c.x; vv[5]=c.y; vv[6]=c.z; vv[7]=c.w;
    }
    for (int s = wave; s < d.cnt; s += 4) {
        const float* krow = d.Kp + ((size_t)b * d.Sb + d.s0 + s) * DM + lane * 8;
        const float4 ka = ((const float4*)krow)[0];
        const float4 kb = ((const float4*)krow)[1];
        float acc = 0.f;
        acc = fmaf(vv[0], fast_tanh(qp[0] + ka.x), acc);
        acc = fmaf(vv[1], fast_tanh(qp[1] + ka.y), acc);
        acc = fmaf(vv[2], fast_tanh(qp[2] + ka.z), acc);
        acc = fmaf(vv[3], fast_tanh(qp[3] + ka.w), acc);
        acc = fmaf(vv[4], fast_tanh(qp[4] + kb.x), acc);
        acc = fmaf(vv[5], fast_tanh(qp[5] + kb.y), acc);
        acc = fmaf(vv[6], fast_tanh(qp[6] + kb.z), acc);
        acc = fmaf(vv[7], fast_tanh(qp[7] + kb.w), acc);
        #pragma unroll
        for (int off = 32; off; off >>= 1) acc += __shfl_xor(acc, off);
        if (lane == 0) scb[(size_t)bt * SRC_TOT + d.off + s] = acc;
    }
}

// ---------------------------------------------------------------------------
// Merged attention-finish + mixture: one block (512 threads) per (b,t).
// ---------------------------------------------------------------------------
__global__ __launch_bounds__(512) void attn2mix_kernel(
    const float* __restrict__ scb,
    const float* __restrict__ Mq, const float* __restrict__ Mqa,
    const float* __restrict__ Mp, const float* __restrict__ Mnlg,
    const float* __restrict__ Wm, const float* __restrict__ bm,
    float* __restrict__ dQ, float* __restrict__ dQA, float* __restrict__ dP,
    float* __restrict__ lam_ws, float* __restrict__ lam_out)
{
    __shared__ float a_sh[SRC_TOT];
    __shared__ float cQ[DM], cA[DM], cP[DM];
    __shared__ float red[16];
    __shared__ float redm[32];
    const int bt   = blockIdx.x;
    const int b    = bt / TT;
    const int tid  = threadIdx.x;
    const int lane = tid & 63;
    const int wave = tid >> 6;          // 0..7
    const float* srow = scb + (size_t)bt * SRC_TOT;

    #pragma unroll
    for (int br = 0; br < 3; ++br) {
        const int off = (br == 0) ? 0 : (br == 1) ? JJ : (JJ + NN);
        const int cnt = (br == 0) ? JJ : (br == 1) ? NN : LL;
        float x = (tid < cnt) ? srow[off + tid] : -INFINITY;
        float m = x;
        #pragma unroll
        for (int o = 32; o; o >>= 1) m = fmaxf(m, __shfl_xor(m, o));
        if (lane == 0) red[wave] = m;
        __syncthreads();
        m = red[0];
        #pragma unroll
        for (int w = 1; w < 8; ++w) m = fmaxf(m, red[w]);
        float e = (tid < cnt) ? __expf(x - m) : 0.f;
        float ss = e;
        #pragma unroll
        for (int o = 32; o; o >>= 1) ss += __shfl_xor(ss, o);
        if (lane == 0) red[8 + wave] = ss;
        __syncthreads();
        float denom = 0.f;
        #pragma unroll
        for (int w = 0; w < 8; ++w) denom += red[8 + w];
        if (tid < cnt) {
            const float a = e / denom;
            a_sh[off + tid] = a;
            float* dst = (br == 0) ? dQ : (br == 1) ? dQA : dP;
            dst[(size_t)bt * cnt + tid] = a;
        }
        __syncthreads();
    }
    // ctx for d = tid (0..511), kept in LDS
    {
        float aQ = 0.f, aA = 0.f, aP = 0.f;
        for (int s = 0; s < JJ; ++s)
            aQ = fmaf(a_sh[s],           Mq [((size_t)b * JJ + s) * DM + tid], aQ);
        for (int s = 0; s < NN; ++s)
            aA = fmaf(a_sh[JJ + s],      Mqa[((size_t)b * NN + s) * DM + tid], aA);
        for (int s = 0; s < LL; ++s)
            aP = fmaf(a_sh[JJ + NN + s], Mp [((size_t)b * LL + s) * DM + tid], aP);
        cQ[tid] = aQ; cA[tid] = aA; cP[tid] = aP;
    }
    __syncthreads();
    // mix: thread handles k = tid, tid+512, tid+1024, tid+1536
    {
        const float x0 = Mnlg[(size_t)bt * DM + tid];
        const float x1 = cQ[tid], x2 = cA[tid], x3 = cP[tid];
        const float4 w0 = *(const float4*)&Wm[(size_t)tid * 4];
        const float4 w1 = *(const float4*)&Wm[(size_t)(512 + tid) * 4];
        const float4 w2 = *(const float4*)&Wm[(size_t)(1024 + tid) * 4];
        const float4 w3 = *(const float4*)&Wm[(size_t)(1536 + tid) * 4];
        float acc[4];
        acc[0] = x0 * w0.x + x1 * w1.x + x2 * w2.x + x3 * w3.x;
        acc[1] = x0 * w0.y + x1 * w1.y + x2 * w2.y + x3 * w3.y;
        acc[2] = x0 * w0.z + x1 * w1.z + x2 * w2.z + x3 * w3.z;
        acc[3] = x0 * w0.w + x1 * w1.w + x2 * w2.w + x3 * w3.w;
        #pragma unroll
        for (int c = 0; c < 4; ++c)
            #pragma unroll
            for (int o = 32; o; o >>= 1) acc[c] += __shfl_xor(acc[c], o);
        if (lane == 0) {
            redm[wave * 4 + 0] = acc[0]; redm[wave * 4 + 1] = acc[1];
            redm[wave * 4 + 2] = acc[2]; redm[wave * 4 + 3] = acc[3];
        }
        __syncthreads();
        if (tid == 0) {
            float l[4];
            #pragma unroll
            for (int c = 0; c < 4; ++c) {
                float s = bm[c];
                #pragma unroll
                for (int w = 0; w < 8; ++w) s += redm[w * 4 + c];
                l[c] = s;
            }
            const float mx = fmaxf(fmaxf(l[0], l[1]), fmaxf(l[2], l[3]));
            const float e0 = __expf(l[0] - mx), e1 = __expf(l[1] - mx);
            const float e2 = __expf(l[2] - mx), e3 = __expf(l[3] - mx);
            const float inv = 1.f / (e0 + e1 + e2 + e3);
            lam_ws[bt * 4 + 0] = e0 * inv; lam_out[bt * 4 + 0] = e0 * inv;
            lam_ws[bt * 4 + 1] = e1 * inv; lam_out[bt * 4 + 1] = e1 * inv;
            lam_ws[bt * 4 + 2] = e2 * inv; lam_out[bt * 4 + 2] = e2 * inv;
            lam_ws[bt * 4 + 3] = e3 * inv; lam_out[bt * 4 + 3] = e3 * inv;
        }
    }
}

// ---------------------------------------------------------------------------
// Merged row write + scatter: one block (1024 thr) per row.
// ---------------------------------------------------------------------------
__global__ __launch_bounds__(1024) void writescatter_kernel(
    const short* __restrict__ logits, const void* __restrict__ smask,
    const float* __restrict__ pstat, const float* __restrict__ lam,
    const float* __restrict__ dP, const float* __restrict__ dQ,
    const float* __restrict__ dQA, const void* __restrict__ src_ext,
    float* __restrict__ out)
{
    const bool byteLayout = (((const int*)smask)[1] == 0x01010101);
    const int r = blockIdx.x;
    float m = -INFINITY;
    for (int c = 0; c < NT; ++c) m = fmaxf(m, pstat[((size_t)r * NT + c) * 2]);
    float dsum = 0.f;
    for (int c = 0; c < NT; ++c) {
        const float pm = pstat[((size_t)r * NT + c) * 2];
        const float ps = pstat[((size_t)r * NT + c) * 2 + 1];
        if (ps > 0.f) dsum += ps * __expf(pm - m);
    }
    const float inv = lam[r * 4 + 0] / dsum;

    const short* lrow = logits + (size_t)r * DFIX;
    float* orow = out + (size_t)r * DEXT;
    const int tid = threadIdx.x;
    #pragma unroll
    for (int k = 0; k < 4; ++k) {
        const int i = (k * 1024 + tid) * 8;
        if (i >= DEXT) continue;
        float4 o0 = make_float4(0.f, 0.f, 0.f, 0.f);
        float4 o1 = make_float4(0.f, 0.f, 0.f, 0.f);
        if (i < DFIX) {                 // 30000 % 8 == 0: no straddle
            const bf16x8 v = *(const bf16x8*)&lrow[i];
            int mb[8]; mask8(smask, byteLayout, i, mb);
            o0.x = mb[0] ? __expf(bf2f(v[0]) - m) * inv : 0.f;
            o0.y = mb[1] ? __expf(bf2f(v[1]) - m) * inv : 0.f;
            o0.z = mb[2] ? __expf(bf2f(v[2]) - m) * inv : 0.f;
            o0.w = mb[3] ? __expf(bf2f(v[3]) - m) * inv : 0.f;
            o1.x = mb[4] ? __expf(bf2f(v[4]) - m) * inv : 0.f;
            o1.y = mb[5] ? __expf(bf2f(v[5]) - m) * inv : 0.f;
            o1.z = mb[6] ? __expf(bf2f(v[6]) - m) * inv : 0.f;
            o1.w = mb[7] ? __expf(bf2f(v[7]) - m) * inv : 0.f;
        }
        *(float4*)&orow[i]     = o0;
        *(float4*)&orow[i + 4] = o1;
    }
    __syncthreads();
    if (tid < SRC_TOT) {
        const int* s32 = (const int*)src_ext;
        const bool src64 = (s32[1] == 0 && s32[3] == 0 && s32[5] == 0 && s32[7] == 0);
        const int b = r / TT;
        const float lamq  = lam[r * 4 + 1];
        const float lamqa = lam[r * 4 + 2];
        const float lamp  = lam[r * 4 + 3];
        const int pos = b * SRC_TOT + tid;
        const int idx = src64 ? (int)((const long long*)src_ext)[pos] : s32[pos];
        float val;
        if      (tid < LL)      val = dP [(size_t)r * LL + tid]             * lamp;
        else if (tid < LL + JJ) val = dQ [(size_t)r * JJ + (tid - LL)]      * lamq;
        else                    val = dQA[(size_t)r * NN + (tid - LL - JJ)] * lamqa;
        atomicAdd(&orow[idx], val);
    }
}

// ---------------------------------------------------------------------------
extern "C" void kernel_launch(void* const* d_in, const int* in_sizes, int n_in,
                              void* d_out, int out_size, void* d_ws, size_t ws_size,
                              hipStream_t stream)
{
    const float* Mp   = (const float*)d_in[0];
    const float* Mq   = (const float*)d_in[1];
    const float* Mqa  = (const float*)d_in[2];
    const float* Mnlg = (const float*)d_in[3];
    const void* src_ext = d_in[7];
    const void* smask   = d_in[8];
    const float* Wk_q = (const float*)d_in[10];
    const float* bk_q = (const float*)d_in[11];
    const float* Wq_q = (const float*)d_in[12];
    const float* bq_q = (const float*)d_in[13];
    const float* v_q  = (const float*)d_in[14];
    const float* Wk_a = (const float*)d_in[15];
    const float* bk_a = (const float*)d_in[16];
    const float* Wq_a = (const float*)d_in[17];
    const float* bq_a = (const float*)d_in[18];
    const float* v_a  = (const float*)d_in[19];
    const float* Wk_p = (const float*)d_in[20];
    const float* bk_p = (const float*)d_in[21];
    const float* Wq_p = (const float*)d_in[22];
    const float* bq_p = (const float*)d_in[23];
    const float* v_p  = (const float*)d_in[24];
    const float* W1   = (const float*)d_in[25];
    const float* b1   = (const float*)d_in[26];
    const float* W2   = (const float*)d_in[27];
    const float* Wm   = (const float*)d_in[28];
    const float* bm   = (const float*)d_in[29];
    float* out = (float*)d_out;

    char* ws = (char*)d_ws;
    size_t off = 0;
    auto alloc = [&](size_t bytes) -> char* {
        char* p = ws + off;
        off += (bytes + 255) & ~(size_t)255;
        return p;
    };
    short* logits = (short*)alloc((size_t)ROWS * DFIX * 2);   // bf16
    float* KpP    = (float*)alloc((size_t)BS * LL * DM * 4);
    float* KpQ    = (float*)alloc((size_t)BS * JJ * DM * 4);
    float* KpA    = (float*)alloc((size_t)BS * NN * DM * 4);
    float* QpQ    = (float*)alloc((size_t)ROWS * DM * 4);
    float* QpA    = (float*)alloc((size_t)ROWS * DM * 4);
    float* QpP    = (float*)alloc((size_t)ROWS * DM * 4);
    float* Hh     = (float*)alloc((size_t)ROWS * DEMB * 4);
    float* dP     = (float*)alloc((size_t)ROWS * LL * 4);
    float* dQ     = (float*)alloc((size_t)ROWS * JJ * 4);
    float* dQA    = (float*)alloc((size_t)ROWS * NN * 4);
    float* lam    = (float*)alloc((size_t)ROWS * 4 * 4);
    float* pstat  = (float*)alloc((size_t)ROWS * NT * 2 * 4);
    float* scb    = (float*)alloc((size_t)ROWS * SRC_TOT * 4);
    short* tWkq = (short*)alloc((size_t)DM * DM * 2);
    short* tWqq = (short*)alloc((size_t)DM * DM * 2);
    short* tWka = (short*)alloc((size_t)DM * DM * 2);
    short* tWqa = (short*)alloc((size_t)DM * DM * 2);
    short* tWkp = (short*)alloc((size_t)DM * DM * 2);
    short* tWqp = (short*)alloc((size_t)DM * DM * 2);
    short* tW1  = (short*)alloc((size_t)DEMB * DM * 2);
    short* tW2  = (short*)alloc((size_t)DFIX * 320 * 2);
    (void)ws_size; (void)in_sizes; (void)n_in; (void)out_size;

    // ---- prep: transpose+cast weights
    PArgs pa;
    pa.nd = 8;
    pa.d[0] = { Wk_p, tWkp, DM,   DM,   DM,  8,  64 };
    pa.d[1] = { Wk_q, tWkq, DM,   DM,   DM,  8,  64 };
    pa.d[2] = { Wk_a, tWka, DM,   DM,   DM,  8,  64 };
    pa.d[3] = { Wq_q, tWqq, DM,   DM,   DM,  8,  64 };
    pa.d[4] = { Wq_a, tWqa, DM,   DM,   DM,  8,  64 };
    pa.d[5] = { Wq_p, tWqp, DM,   DM,   DM,  8,  64 };
    pa.d[6] = { W1,   tW1,  DM,   DEMB, DM,  5,  40 };
    pa.d[7] = { W2,   tW2,  DEMB, DFIX, 320, 469, 2345 };
    prep_kernel<<<64 * 6 + 40 + 2345, 256, 0, stream>>>(pa);

    // ---- launch A: Hh = Mnlg @ W1 + b1
    GArgs gA;
    gA.nd = 1;
    gA.d[0] = { Mnlg, tW1, b1, Hh, nullptr, nullptr,
                ROWS, DEMB, DM, DM, 3, 0, 0, 0, 9 };
    gemm_bf16_kernel<<<9, 256, 0, stream>>>(gA);

    // ---- launch B: projections (long-K) first, logits (short-K, fused stats) last
    GArgs gB;
    gB.nd = 7;
    gB.d[0] = { Mp,   tWkp, bk_p,    KpP,    nullptr, nullptr,
                BS*LL, DM,   DM,   DM,  4,   0, 0, 0,  64 };
    gB.d[1] = { Mq,   tWkq, bk_q,    KpQ,    nullptr, nullptr,
                BS*JJ, DM,   DM,   DM,  4,   0, 0, 0,  12 };
    gB.d[2] = { Mqa,  tWka, bk_a,    KpA,    nullptr, nullptr,
                BS*NN, DM,   DM,   DM,  4,   0, 0, 0,   8 };
    gB.d[3] = { Mnlg, tWqq, bq_q,    QpQ,    nullptr, nullptr,
                ROWS,  DM,   DM,   DM,  4,   0, 0, 0,  12 };
    gB.d[4] = { Mnlg, tWqa, bq_a,    QpA,    nullptr, nullptr,
                ROWS,  DM,   DM,   DM,  4,   0, 0, 0,  12 };
    gB.d[5] = { Mnlg, tWqp, bq_p,    QpP,    nullptr, nullptr,
                ROWS,  DM,   DM,   DM,  4,   0, 0, 0,  12 };
    gB.d[6] = { Hh,   tW2,  nullptr, logits, smask,   pstat,
                ROWS,  DFIX, DEMB, 320, 235, 3, 1, NT, 705 };
    gemm_bf16_kernel<<<825, 256, 0, stream>>>(gB);

    // ---- attention: load-balanced scores, then finish+mix
    SArgs sa;
    sa.c[0] = { KpQ, QpQ, v_q, JJ,   0, JJ,  0 };
    sa.c[1] = { KpA, QpA, v_a, NN,   0, NN,  JJ };
    sa.c[2] = { KpP, QpP, v_p, LL,   0, 64,  JJ + NN };
    sa.c[3] = { KpP, QpP, v_p, LL,  64, 64,  JJ + NN + 64 };
    sa.c[4] = { KpP, QpP, v_p, LL, 128, 64,  JJ + NN + 128 };
    sa.c[5] = { KpP, QpP, v_p, LL, 192, 64,  JJ + NN + 192 };
    scores_kernel<<<dim3(ROWS, 6), 256, 0, stream>>>(sa, scb);
    attn2mix_kernel<<<ROWS, 512, 0, stream>>>(scb, Mq, Mqa, Mp, Mnlg, Wm, bm,
                                              dQ, dQA, dP, lam,
                                              out + (size_t)ROWS * DEXT);

    // ---- merged row write + scatter
    writescatter_kernel<<<ROWS, 1024, 0, stream>>>(
        logits, smask, pstat, lam, dP, dQ, dQA, src_ext, out);
}

// Round 12
// 161.925 us; speedup vs baseline: 1.5764x; 1.3466x over previous
//
#include <hip/hip_runtime.h>
#include <math.h>

// ---------------------------------------------------------------------------
// Problem constants
// ---------------------------------------------------------------------------
#define BS     8
#define LL     256
#define JJ     48
#define NN     32
#define TT     48
#define DM     512
#define DEMB   300
#define DFIX   30000
#define DEXT   32000
#define SRC_TOT (LL + JJ + NN)      // 336
#define ROWS   (BS * TT)            // 384
#define NT     235                  // logits n-tiles (235*128 = 30080)

typedef float f32x4  __attribute__((ext_vector_type(4)));
typedef short bf16x8 __attribute__((ext_vector_type(8)));

__device__ __forceinline__ short f2bf(float f) {
    union { float f; unsigned u; } v; v.f = f;
    return (short)((v.u + 0x7FFFu + ((v.u >> 16) & 1u)) >> 16);  // RNE
}
__device__ __forceinline__ float bf2f(short s) {
    union { unsigned u; float f; } v;
    v.u = ((unsigned)(unsigned short)s) << 16;
    return v.f;
}
__device__ __forceinline__ float fast_exp2(float x) {
#if __has_builtin(__builtin_amdgcn_exp2f)
    return __builtin_amdgcn_exp2f(x);
#else
    return exp2f(x);
#endif
}
__device__ __forceinline__ float fast_rcp(float x) {
#if __has_builtin(__builtin_amdgcn_rcpf)
    return __builtin_amdgcn_rcpf(x);
#else
    return 1.f / x;
#endif
}
__device__ __forceinline__ float fast_tanh(float x) {
    x = fminf(fmaxf(x, -15.f), 15.f);
    const float e = fast_exp2(x * 2.885390082f);
    return (e - 1.f) * fast_rcp(e + 1.f);
}
__device__ __forceinline__ bool smask_true(const void* smask, bool byteLayout, int i)
{
    if (byteLayout) return ((const unsigned char*)smask)[i] != 0;
    return ((const int*)smask)[i] != 0;
}
__device__ __forceinline__ void mask8(const void* smask, bool byteLayout, int i,
                                      int* mb)
{
    if (byteLayout) {
        const uchar4 a = ((const uchar4*)((const unsigned char*)smask + i))[0];
        const uchar4 b = ((const uchar4*)((const unsigned char*)smask + i))[1];
        mb[0]=a.x; mb[1]=a.y; mb[2]=a.z; mb[3]=a.w;
        mb[4]=b.x; mb[5]=b.y; mb[6]=b.z; mb[7]=b.w;
    } else {
        const int* p = (const int*)smask + i;
        #pragma unroll
        for (int j = 0; j < 8; ++j) mb[j] = p[j];
    }
}

// ---------------------------------------------------------------------------
// Weight prep: W[K][N] fp32 -> Wt[N][Kp] bf16 (zero-filled to Kp).
// Write phase: thread owns (row, 16-elem k-chunk) -> 2x contiguous 16B
// stores; 4-thread groups cover 128B contiguous (coalesced).
// ---------------------------------------------------------------------------
struct PDesc { const float* src; short* dst; int K, N, Kp, ntx, tiles; };
struct PArgs { PDesc d[8]; int nd; };

__global__ __launch_bounds__(256) void prep_kernel(PArgs pa)
{
    __shared__ short T[64][72];
    int tile = blockIdx.x, g = 0;
    while (g + 1 < pa.nd && tile >= pa.d[g].tiles) { tile -= pa.d[g].tiles; ++g; }
    const PDesc d = pa.d[g];
    const int kt = tile / d.ntx, nt = tile % d.ntx;
    const int k0 = kt * 64, n0 = nt * 64;
    const int tid = threadIdx.x;
    {
        const int n = n0 + (tid & 63);
        #pragma unroll
        for (int p = 0; p < 16; ++p) {
            const int kk = p * 4 + (tid >> 6);
            const int k = k0 + kk;
            float v = 0.f;
            if (k < d.K && n < d.N) v = d.src[(size_t)k * d.N + n];
            T[kk][tid & 63] = f2bf(v);
        }
    }
    __syncthreads();
    {
        const int nn = tid >> 2;          // 0..63
        const int kq = (tid & 3) * 16;    // 0,16,32,48
        const int n = n0 + nn;
        if (n < d.N) {
            bf16x8 v0, v1;
            #pragma unroll
            for (int j = 0; j < 8; ++j) v0[j] = T[kq + j][nn];
            #pragma unroll
            for (int j = 0; j < 8; ++j) v1[j] = T[kq + 8 + j][nn];
            *(bf16x8*)&d.dst[(size_t)n * d.Kp + k0 + kq]     = v0;
            *(bf16x8*)&d.dst[(size_t)n * d.Kp + k0 + kq + 8] = v1;
        }
    }
}

// ---------------------------------------------------------------------------
// Batched bf16-MFMA GEMM v4: C[M,N] = A[M,K]@B[K,N] (+bias); fp32 A,
// bf16 Wt[N][Kp] B; C fp32 or bf16 (obf). 128x128 tile, BK=32, dbuf LDS
// (row dim padded 130 -> conflict-free staging). obf path also computes
// per-(row, n-tile) masked softmax partials into pstat (fused stats).
// ---------------------------------------------------------------------------
struct GDesc { const float* A; const short* Bt; const float* bias; void* C;
               const void* smask; float* pstat;
               int M, N, K, Kp, nx, my, obf, nt, tiles; };
struct GArgs { GDesc d[7]; int nd; };

__global__ __launch_bounds__(256) void gemm_bf16_kernel(GArgs ga)
{
    __shared__ short As[2][4][130][8];
    __shared__ short Bs[2][4][130][8];
    __shared__ float pm_s[128][2];
    __shared__ float ps_s[128][2];

    int tile = blockIdx.x, g = 0;
    while (g + 1 < ga.nd && tile >= ga.d[g].tiles) { tile -= ga.d[g].tiles; ++g; }
    const float* __restrict__ A  = ga.d[g].A;
    const short* __restrict__ Bt = ga.d[g].Bt;
    const float* bias = ga.d[g].bias;
    const int N = ga.d[g].N, K = ga.d[g].K, Kp = ga.d[g].Kp;
    const int nx = ga.d[g].nx, my = ga.d[g].my, obf = ga.d[g].obf;

    int bm, bn;
    if (my > 0) { bm = (tile % my) * 128; bn = (tile / my) * 128; }
    else        { bm = (tile / nx) * 128; bn = (tile % nx) * 128; }
    const int tid  = threadIdx.x;
    const int lane = tid & 63;
    const int wv   = tid >> 6;
    const int wm   = (wv >> 1) * 64;
    const int wn   = (wv & 1) * 64;

    const int a_kq  = (tid & 7) * 4;
    const int a_row = tid >> 3;
    float4  ra[4];
    bf16x8  rb[2];

    auto loadA = [&](int k0) {
        #pragma unroll
        for (int p = 0; p < 4; ++p) {
            const int row = p * 32 + a_row;
            const int gk = k0 + a_kq;
            const float* ap = A + (size_t)(bm + row) * K + gk;
            float4 a = make_float4(0.f, 0.f, 0.f, 0.f);
            if (gk + 3 < K) a = *(const float4*)ap;
            else {
                if (gk     < K) a.x = ap[0];
                if (gk + 1 < K) a.y = ap[1];
                if (gk + 2 < K) a.z = ap[2];
                if (gk + 3 < K) a.w = ap[3];
            }
            ra[p] = a;
        }
    };
    auto loadB = [&](int k0) {
        #pragma unroll
        for (int p = 0; p < 2; ++p) {
            const int idx = p * 256 + tid;
            const int n = idx >> 2, kb = idx & 3;
            const int gn = bn + n;
            bf16x8 v = {};
            if (gn < N) v = *(const bf16x8*)&Bt[(size_t)gn * Kp + k0 + kb * 8];
            rb[p] = v;
        }
    };
    auto storeA = [&](int buf) {
        const int kb = a_kq >> 3, ko = a_kq & 7;
        #pragma unroll
        for (int p = 0; p < 4; ++p) {
            const int row = p * 32 + a_row;
            short4 s = { f2bf(ra[p].x), f2bf(ra[p].y), f2bf(ra[p].z), f2bf(ra[p].w) };
            *(short4*)&As[buf][kb][row][ko] = s;
        }
    };
    auto storeB = [&](int buf) {
        #pragma unroll
        for (int p = 0; p < 2; ++p) {
            const int idx = p * 256 + tid;
            const int n = idx >> 2, kb = idx & 3;
            *(bf16x8*)&Bs[buf][kb][n][0] = rb[p];
        }
    };

    f32x4 acc[4][4] = {};
    const int nk = Kp / 32;

    loadA(0); loadB(0);
    storeA(0); storeB(0);
    __syncthreads();

    for (int kk = 0; kk < nk; ++kk) {
        const int cur = kk & 1;
        if (kk + 1 < nk) { loadA((kk + 1) * 32); loadB((kk + 1) * 32); }
        bf16x8 af[4], bfr[4];
        #pragma unroll
        for (int i = 0; i < 4; ++i) {
            af[i]  = *(const bf16x8*)&As[cur][lane >> 4][wm + i * 16 + (lane & 15)][0];
            bfr[i] = *(const bf16x8*)&Bs[cur][lane >> 4][wn + i * 16 + (lane & 15)][0];
        }
        #pragma unroll
        for (int mi = 0; mi < 4; ++mi)
            #pragma unroll
            for (int ni = 0; ni < 4; ++ni)
                acc[mi][ni] = __builtin_amdgcn_mfma_f32_16x16x32_bf16(
                    af[mi], bfr[ni], acc[mi][ni], 0, 0, 0);
        if (kk + 1 < nk) { storeA(cur ^ 1); storeB(cur ^ 1); }
        __syncthreads();
    }

    if (!obf) {
        float* Cf = (float*)ga.d[g].C;
        #pragma unroll
        for (int ni = 0; ni < 4; ++ni) {
            const int gn = bn + wn + ni * 16 + (lane & 15);
            if (gn >= N) continue;
            const float bb = bias ? bias[gn] : 0.f;
            #pragma unroll
            for (int mi = 0; mi < 4; ++mi)
                #pragma unroll
                for (int r = 0; r < 4; ++r) {
                    const int gm = bm + wm + mi * 16 + (lane >> 4) * 4 + r;
                    Cf[(size_t)gm * N + gn] = acc[mi][ni][r] + bb;
                }
        }
    } else {
        // bf16 C write + fused masked softmax partials (no bias on this path)
        short* Cs = (short*)ga.d[g].C;
        const void* sm = ga.d[g].smask;
        const bool byteLayout = (((const int*)sm)[1] == 0x01010101);
        int mk[4];
        #pragma unroll
        for (int ni = 0; ni < 4; ++ni) {
            const int gn = bn + wn + ni * 16 + (lane & 15);
            const bool inb = (gn < N);
            mk[ni] = inb && smask_true(sm, byteLayout, inb ? gn : 0);
            if (inb) {
                #pragma unroll
                for (int mi = 0; mi < 4; ++mi)
                    #pragma unroll
                    for (int r = 0; r < 4; ++r) {
                        const int gm = bm + wm + mi * 16 + (lane >> 4) * 4 + r;
                        Cs[(size_t)gm * N + gn] = f2bf(acc[mi][ni][r]);
                    }
            }
        }
        #pragma unroll
        for (int mi = 0; mi < 4; ++mi) {
            #pragma unroll
            for (int r = 0; r < 4; ++r) {
                const int rl = wm + mi * 16 + (lane >> 4) * 4 + r;  // 0..127
                float vmax = -INFINITY;
                #pragma unroll
                for (int ni = 0; ni < 4; ++ni)
                    if (mk[ni]) vmax = fmaxf(vmax, acc[mi][ni][r]);
                #pragma unroll
                for (int o = 1; o < 16; o <<= 1)
                    vmax = fmaxf(vmax, __shfl_xor(vmax, o));
                float se = 0.f;
                #pragma unroll
                for (int ni = 0; ni < 4; ++ni)
                    if (mk[ni]) se += __expf(acc[mi][ni][r] - vmax);
                #pragma unroll
                for (int o = 1; o < 16; o <<= 1)
                    se += __shfl_xor(se, o);
                if ((lane & 15) == 0) {
                    pm_s[rl][wn >> 6] = vmax;
                    ps_s[rl][wn >> 6] = se;
                }
            }
        }
        __syncthreads();
        if (tid < 128) {
            const float mA = pm_s[tid][0], mB = pm_s[tid][1];
            const float sA = ps_s[tid][0], sB = ps_s[tid][1];
            const float m = fmaxf(mA, mB);
            float s = 0.f;
            if (sA > 0.f) s += sA * __expf(mA - m);
            if (sB > 0.f) s += sB * __expf(mB - m);
            float* ps = ga.d[g].pstat;
            const size_t idx = ((size_t)(bm + tid) * ga.d[g].nt + (bn >> 7)) * 2;
            ps[idx + 0] = m;
            ps[idx + 1] = s;
        }
    }
}

// ---------------------------------------------------------------------------
// Combine the NT per-tile partials per row -> stat[r] = (m_row, lam_v/denom).
// One wave per row; lane-strided parallel reduce.
// ---------------------------------------------------------------------------
__global__ __launch_bounds__(64) void combine_kernel(
    const float* __restrict__ pstat, const float* __restrict__ lam,
    float* __restrict__ stat)
{
    const int r = blockIdx.x;
    const int lane = threadIdx.x;
    float m = -INFINITY;
    for (int c = lane; c < NT; c += 64)
        m = fmaxf(m, pstat[((size_t)r * NT + c) * 2]);
    #pragma unroll
    for (int o = 32; o; o >>= 1) m = fmaxf(m, __shfl_xor(m, o));
    float s = 0.f;
    for (int c = lane; c < NT; c += 64) {
        const float pm = pstat[((size_t)r * NT + c) * 2];
        const float ps = pstat[((size_t)r * NT + c) * 2 + 1];
        if (ps > 0.f) s += ps * __expf(pm - m);
    }
    #pragma unroll
    for (int o = 32; o; o >>= 1) s += __shfl_xor(s, o);
    if (lane == 0) {
        stat[r * 2 + 0] = m;
        stat[r * 2 + 1] = lam[r * 4 + 0] / s;
    }
}

// ---------------------------------------------------------------------------
// Attention scores, load-balanced: grid (ROWS, 6 chunks), 256 threads.
// ---------------------------------------------------------------------------
struct SDesc { const float* Kp; const float* Qp; const float* vv;
               int Sb, s0, cnt, off; };
struct SArgs { SDesc c[6]; };

__global__ __launch_bounds__(256) void scores_kernel(SArgs sa,
                                                     float* __restrict__ scb)
{
    const SDesc d = sa.c[blockIdx.y];
    const int bt   = blockIdx.x;
    const int b    = bt / TT;
    const int tid  = threadIdx.x;
    const int lane = tid & 63;
    const int wave = tid >> 6;

    float qp[8], vv[8];
    {
        const float4* q4 = (const float4*)(d.Qp + (size_t)bt * DM) + lane * 2;
        float4 a = q4[0], c = q4[1];
        qp[0]=a.x; qp[1]=a.y; qp[2]=a.z; qp[3]=a.w;
        qp[4]=c.x; qp[5]=c.y; qp[6]=c.z; qp[7]=c.w;
        const float4* v4 = (const float4*)d.vv + lane * 2;
        a = v4[0]; c = v4[1];
        vv[0]=a.x; vv[1]=a.y; vv[2]=a.z; vv[3]=a.w;
        vv[4]=c.x; vv[5]=c.y; vv[6]=c.z; vv[7]=c.w;
    }
    for (int s = wave; s < d.cnt; s += 4) {
        const float* krow = d.Kp + ((size_t)b * d.Sb + d.s0 + s) * DM + lane * 8;
        const float4 ka = ((const float4*)krow)[0];
        const float4 kb = ((const float4*)krow)[1];
        float acc = 0.f;
        acc = fmaf(vv[0], fast_tanh(qp[0] + ka.x), acc);
        acc = fmaf(vv[1], fast_tanh(qp[1] + ka.y), acc);
        acc = fmaf(vv[2], fast_tanh(qp[2] + ka.z), acc);
        acc = fmaf(vv[3], fast_tanh(qp[3] + ka.w), acc);
        acc = fmaf(vv[4], fast_tanh(qp[4] + kb.x), acc);
        acc = fmaf(vv[5], fast_tanh(qp[5] + kb.y), acc);
        acc = fmaf(vv[6], fast_tanh(qp[6] + kb.z), acc);
        acc = fmaf(vv[7], fast_tanh(qp[7] + kb.w), acc);
        #pragma unroll
        for (int off = 32; off; off >>= 1) acc += __shfl_xor(acc, off);
        if (lane == 0) scb[(size_t)bt * SRC_TOT + d.off + s] = acc;
    }
}

// ---------------------------------------------------------------------------
// Merged attention-finish + mixture: one block (512 threads) per (b,t).
// ---------------------------------------------------------------------------
__global__ __launch_bounds__(512) void attn2mix_kernel(
    const float* __restrict__ scb,
    const float* __restrict__ Mq, const float* __restrict__ Mqa,
    const float* __restrict__ Mp, const float* __restrict__ Mnlg,
    const float* __restrict__ Wm, const float* __restrict__ bm,
    float* __restrict__ dQ, float* __restrict__ dQA, float* __restrict__ dP,
    float* __restrict__ lam_ws, float* __restrict__ lam_out)
{
    __shared__ float a_sh[SRC_TOT];
    __shared__ float cQ[DM], cA[DM], cP[DM];
    __shared__ float red[16];
    __shared__ float redm[32];
    const int bt   = blockIdx.x;
    const int b    = bt / TT;
    const int tid  = threadIdx.x;
    const int lane = tid & 63;
    const int wave = tid >> 6;          // 0..7
    const float* srow = scb + (size_t)bt * SRC_TOT;

    #pragma unroll
    for (int br = 0; br < 3; ++br) {
        const int off = (br == 0) ? 0 : (br == 1) ? JJ : (JJ + NN);
        const int cnt = (br == 0) ? JJ : (br == 1) ? NN : LL;
        float x = (tid < cnt) ? srow[off + tid] : -INFINITY;
        float m = x;
        #pragma unroll
        for (int o = 32; o; o >>= 1) m = fmaxf(m, __shfl_xor(m, o));
        if (lane == 0) red[wave] = m;
        __syncthreads();
        m = red[0];
        #pragma unroll
        for (int w = 1; w < 8; ++w) m = fmaxf(m, red[w]);
        float e = (tid < cnt) ? __expf(x - m) : 0.f;
        float ss = e;
        #pragma unroll
        for (int o = 32; o; o >>= 1) ss += __shfl_xor(ss, o);
        if (lane == 0) red[8 + wave] = ss;
        __syncthreads();
        float denom = 0.f;
        #pragma unroll
        for (int w = 0; w < 8; ++w) denom += red[8 + w];
        if (tid < cnt) {
            const float a = e / denom;
            a_sh[off + tid] = a;
            float* dst = (br == 0) ? dQ : (br == 1) ? dQA : dP;
            dst[(size_t)bt * cnt + tid] = a;
        }
        __syncthreads();
    }
    // ctx for d = tid (0..511), kept in LDS
    {
        float aQ = 0.f, aA = 0.f, aP = 0.f;
        for (int s = 0; s < JJ; ++s)
            aQ = fmaf(a_sh[s],           Mq [((size_t)b * JJ + s) * DM + tid], aQ);
        for (int s = 0; s < NN; ++s)
            aA = fmaf(a_sh[JJ + s],      Mqa[((size_t)b * NN + s) * DM + tid], aA);
        for (int s = 0; s < LL; ++s)
            aP = fmaf(a_sh[JJ + NN + s], Mp [((size_t)b * LL + s) * DM + tid], aP);
        cQ[tid] = aQ; cA[tid] = aA; cP[tid] = aP;
    }
    __syncthreads();
    // mix: thread handles k = tid, tid+512, tid+1024, tid+1536
    {
        const float x0 = Mnlg[(size_t)bt * DM + tid];
        const float x1 = cQ[tid], x2 = cA[tid], x3 = cP[tid];
        const float4 w0 = *(const float4*)&Wm[(size_t)tid * 4];
        const float4 w1 = *(const float4*)&Wm[(size_t)(512 + tid) * 4];
        const float4 w2 = *(const float4*)&Wm[(size_t)(1024 + tid) * 4];
        const float4 w3 = *(const float4*)&Wm[(size_t)(1536 + tid) * 4];
        float acc[4];
        acc[0] = x0 * w0.x + x1 * w1.x + x2 * w2.x + x3 * w3.x;
        acc[1] = x0 * w0.y + x1 * w1.y + x2 * w2.y + x3 * w3.y;
        acc[2] = x0 * w0.z + x1 * w1.z + x2 * w2.z + x3 * w3.z;
        acc[3] = x0 * w0.w + x1 * w1.w + x2 * w2.w + x3 * w3.w;
        #pragma unroll
        for (int c = 0; c < 4; ++c)
            #pragma unroll
            for (int o = 32; o; o >>= 1) acc[c] += __shfl_xor(acc[c], o);
        if (lane == 0) {
            redm[wave * 4 + 0] = acc[0]; redm[wave * 4 + 1] = acc[1];
            redm[wave * 4 + 2] = acc[2]; redm[wave * 4 + 3] = acc[3];
        }
        __syncthreads();
        if (tid == 0) {
            float l[4];
            #pragma unroll
            for (int c = 0; c < 4; ++c) {
                float s = bm[c];
                #pragma unroll
                for (int w = 0; w < 8; ++w) s += redm[w * 4 + c];
                l[c] = s;
            }
            const float mx = fmaxf(fmaxf(l[0], l[1]), fmaxf(l[2], l[3]));
            const float e0 = __expf(l[0] - mx), e1 = __expf(l[1] - mx);
            const float e2 = __expf(l[2] - mx), e3 = __expf(l[3] - mx);
            const float inv = 1.f / (e0 + e1 + e2 + e3);
            lam_ws[bt * 4 + 0] = e0 * inv; lam_out[bt * 4 + 0] = e0 * inv;
            lam_ws[bt * 4 + 1] = e1 * inv; lam_out[bt * 4 + 1] = e1 * inv;
            lam_ws[bt * 4 + 2] = e2 * inv; lam_out[bt * 4 + 2] = e2 * inv;
            lam_ws[bt * 4 + 3] = e3 * inv; lam_out[bt * 4 + 3] = e3 * inv;
        }
    }
}

// ---------------------------------------------------------------------------
// Merged row write + scatter: one block (1024 thr) per row; stat precombined.
// ---------------------------------------------------------------------------
__global__ __launch_bounds__(1024) void writescatter_kernel(
    const short* __restrict__ logits, const void* __restrict__ smask,
    const float* __restrict__ stat, const float* __restrict__ lam,
    const float* __restrict__ dP, const float* __restrict__ dQ,
    const float* __restrict__ dQA, const void* __restrict__ src_ext,
    float* __restrict__ out)
{
    const bool byteLayout = (((const int*)smask)[1] == 0x01010101);
    const int r = blockIdx.x;
    const float m   = stat[r * 2 + 0];
    const float inv = stat[r * 2 + 1];

    const short* lrow = logits + (size_t)r * DFIX;
    float* orow = out + (size_t)r * DEXT;
    const int tid = threadIdx.x;
    #pragma unroll
    for (int k = 0; k < 4; ++k) {
        const int i = (k * 1024 + tid) * 8;
        if (i >= DEXT) continue;
        float4 o0 = make_float4(0.f, 0.f, 0.f, 0.f);
        float4 o1 = make_float4(0.f, 0.f, 0.f, 0.f);
        if (i < DFIX) {                 // 30000 % 8 == 0: no straddle
            const bf16x8 v = *(const bf16x8*)&lrow[i];
            int mb[8]; mask8(smask, byteLayout, i, mb);
            o0.x = mb[0] ? __expf(bf2f(v[0]) - m) * inv : 0.f;
            o0.y = mb[1] ? __expf(bf2f(v[1]) - m) * inv : 0.f;
            o0.z = mb[2] ? __expf(bf2f(v[2]) - m) * inv : 0.f;
            o0.w = mb[3] ? __expf(bf2f(v[3]) - m) * inv : 0.f;
            o1.x = mb[4] ? __expf(bf2f(v[4]) - m) * inv : 0.f;
            o1.y = mb[5] ? __expf(bf2f(v[5]) - m) * inv : 0.f;
            o1.z = mb[6] ? __expf(bf2f(v[6]) - m) * inv : 0.f;
            o1.w = mb[7] ? __expf(bf2f(v[7]) - m) * inv : 0.f;
        }
        *(float4*)&orow[i]     = o0;
        *(float4*)&orow[i + 4] = o1;
    }
    __syncthreads();
    if (tid < SRC_TOT) {
        const int* s32 = (const int*)src_ext;
        const bool src64 = (s32[1] == 0 && s32[3] == 0 && s32[5] == 0 && s32[7] == 0);
        const int b = r / TT;
        const float lamq  = lam[r * 4 + 1];
        const float lamqa = lam[r * 4 + 2];
        const float lamp  = lam[r * 4 + 3];
        const int pos = b * SRC_TOT + tid;
        const int idx = src64 ? (int)((const long long*)src_ext)[pos] : s32[pos];
        float val;
        if      (tid < LL)      val = dP [(size_t)r * LL + tid]             * lamp;
        else if (tid < LL + JJ) val = dQ [(size_t)r * JJ + (tid - LL)]      * lamq;
        else                    val = dQA[(size_t)r * NN + (tid - LL - JJ)] * lamqa;
        atomicAdd(&orow[idx], val);
    }
}

// ---------------------------------------------------------------------------
extern "C" void kernel_launch(void* const* d_in, const int* in_sizes, int n_in,
                              void* d_out, int out_size, void* d_ws, size_t ws_size,
                              hipStream_t stream)
{
    const float* Mp   = (const float*)d_in[0];
    const float* Mq   = (const float*)d_in[1];
    const float* Mqa  = (const float*)d_in[2];
    const float* Mnlg = (const float*)d_in[3];
    const void* src_ext = d_in[7];
    const void* smask   = d_in[8];
    const float* Wk_q = (const float*)d_in[10];
    const float* bk_q = (const float*)d_in[11];
    const float* Wq_q = (const float*)d_in[12];
    const float* bq_q = (const float*)d_in[13];
    const float* v_q  = (const float*)d_in[14];
    const float* Wk_a = (const float*)d_in[15];
    const float* bk_a = (const float*)d_in[16];
    const float* Wq_a = (const float*)d_in[17];
    const float* bq_a = (const float*)d_in[18];
    const float* v_a  = (const float*)d_in[19];
    const float* Wk_p = (const float*)d_in[20];
    const float* bk_p = (const float*)d_in[21];
    const float* Wq_p = (const float*)d_in[22];
    const float* bq_p = (const float*)d_in[23];
    const float* v_p  = (const float*)d_in[24];
    const float* W1   = (const float*)d_in[25];
    const float* b1   = (const float*)d_in[26];
    const float* W2   = (const float*)d_in[27];
    const float* Wm   = (const float*)d_in[28];
    const float* bm   = (const float*)d_in[29];
    float* out = (float*)d_out;

    char* ws = (char*)d_ws;
    size_t off = 0;
    auto alloc = [&](size_t bytes) -> char* {
        char* p = ws + off;
        off += (bytes + 255) & ~(size_t)255;
        return p;
    };
    short* logits = (short*)alloc((size_t)ROWS * DFIX * 2);   // bf16
    float* KpP    = (float*)alloc((size_t)BS * LL * DM * 4);
    float* KpQ    = (float*)alloc((size_t)BS * JJ * DM * 4);
    float* KpA    = (float*)alloc((size_t)BS * NN * DM * 4);
    float* QpQ    = (float*)alloc((size_t)ROWS * DM * 4);
    float* QpA    = (float*)alloc((size_t)ROWS * DM * 4);
    float* QpP    = (float*)alloc((size_t)ROWS * DM * 4);
    float* Hh     = (float*)alloc((size_t)ROWS * DEMB * 4);
    float* dP     = (float*)alloc((size_t)ROWS * LL * 4);
    float* dQ     = (float*)alloc((size_t)ROWS * JJ * 4);
    float* dQA    = (float*)alloc((size_t)ROWS * NN * 4);
    float* lam    = (float*)alloc((size_t)ROWS * 4 * 4);
    float* pstat  = (float*)alloc((size_t)ROWS * NT * 2 * 4);
    float* stat   = (float*)alloc((size_t)ROWS * 2 * 4);
    float* scb    = (float*)alloc((size_t)ROWS * SRC_TOT * 4);
    short* tWkq = (short*)alloc((size_t)DM * DM * 2);
    short* tWqq = (short*)alloc((size_t)DM * DM * 2);
    short* tWka = (short*)alloc((size_t)DM * DM * 2);
    short* tWqa = (short*)alloc((size_t)DM * DM * 2);
    short* tWkp = (short*)alloc((size_t)DM * DM * 2);
    short* tWqp = (short*)alloc((size_t)DM * DM * 2);
    short* tW1  = (short*)alloc((size_t)DEMB * DM * 2);
    short* tW2  = (short*)alloc((size_t)DFIX * 320 * 2);
    (void)ws_size; (void)in_sizes; (void)n_in; (void)out_size;

    // ---- prep: transpose+cast weights
    PArgs pa;
    pa.nd = 8;
    pa.d[0] = { Wk_p, tWkp, DM,   DM,   DM,  8,  64 };
    pa.d[1] = { Wk_q, tWkq, DM,   DM,   DM,  8,  64 };
    pa.d[2] = { Wk_a, tWka, DM,   DM,   DM,  8,  64 };
    pa.d[3] = { Wq_q, tWqq, DM,   DM,   DM,  8,  64 };
    pa.d[4] = { Wq_a, tWqa, DM,   DM,   DM,  8,  64 };
    pa.d[5] = { Wq_p, tWqp, DM,   DM,   DM,  8,  64 };
    pa.d[6] = { W1,   tW1,  DM,   DEMB, DM,  5,  40 };
    pa.d[7] = { W2,   tW2,  DEMB, DFIX, 320, 469, 2345 };
    prep_kernel<<<64 * 6 + 40 + 2345, 256, 0, stream>>>(pa);

    // ---- launch A: Hh = Mnlg @ W1 + b1
    GArgs gA;
    gA.nd = 1;
    gA.d[0] = { Mnlg, tW1, b1, Hh, nullptr, nullptr,
                ROWS, DEMB, DM, DM, 3, 0, 0, 0, 9 };
    gemm_bf16_kernel<<<9, 256, 0, stream>>>(gA);

    // ---- launch B: projections (long-K) first, logits (short-K, fused stats) last
    GArgs gB;
    gB.nd = 7;
    gB.d[0] = { Mp,   tWkp, bk_p,    KpP,    nullptr, nullptr,
                BS*LL, DM,   DM,   DM,  4,   0, 0, 0,  64 };
    gB.d[1] = { Mq,   tWkq, bk_q,    KpQ,    nullptr, nullptr,
                BS*JJ, DM,   DM,   DM,  4,   0, 0, 0,  12 };
    gB.d[2] = { Mqa,  tWka, bk_a,    KpA,    nullptr, nullptr,
                BS*NN, DM,   DM,   DM,  4,   0, 0, 0,   8 };
    gB.d[3] = { Mnlg, tWqq, bq_q,    QpQ,    nullptr, nullptr,
                ROWS,  DM,   DM,   DM,  4,   0, 0, 0,  12 };
    gB.d[4] = { Mnlg, tWqa, bq_a,    QpA,    nullptr, nullptr,
                ROWS,  DM,   DM,   DM,  4,   0, 0, 0,  12 };
    gB.d[5] = { Mnlg, tWqp, bq_p,    QpP,    nullptr, nullptr,
                ROWS,  DM,   DM,   DM,  4,   0, 0, 0,  12 };
    gB.d[6] = { Hh,   tW2,  nullptr, logits, smask,   pstat,
                ROWS,  DFIX, DEMB, 320, 235, 3, 1, NT, 705 };
    gemm_bf16_kernel<<<825, 256, 0, stream>>>(gB);

    // ---- attention: load-balanced scores, then finish+mix
    SArgs sa;
    sa.c[0] = { KpQ, QpQ, v_q, JJ,   0, JJ,  0 };
    sa.c[1] = { KpA, QpA, v_a, NN,   0, NN,  JJ };
    sa.c[2] = { KpP, QpP, v_p, LL,   0, 64,  JJ + NN };
    sa.c[3] = { KpP, QpP, v_p, LL,  64, 64,  JJ + NN + 64 };
    sa.c[4] = { KpP, QpP, v_p, LL, 128, 64,  JJ + NN + 128 };
    sa.c[5] = { KpP, QpP, v_p, LL, 192, 64,  JJ + NN + 192 };
    scores_kernel<<<dim3(ROWS, 6), 256, 0, stream>>>(sa, scb);
    attn2mix_kernel<<<ROWS, 512, 0, stream>>>(scb, Mq, Mqa, Mp, Mnlg, Wm, bm,
                                              dQ, dQA, dP, lam,
                                              out + (size_t)ROWS * DEXT);

    // ---- combine stats (tiny), then merged row write + scatter
    combine_kernel<<<ROWS, 64, 0, stream>>>(pstat, lam, stat);
    writescatter_kernel<<<ROWS, 1024, 0, stream>>>(
        logits, smask, stat, lam, dP, dQ, dQA, src_ext, out);
}

// Round 13
// 157.242 us; speedup vs baseline: 1.6233x; 1.0298x over previous
//
#include <hip/hip_runtime.h>
#include <math.h>

// ---------------------------------------------------------------------------
// Problem constants
// ---------------------------------------------------------------------------
#define BS     8
#define LL     256
#define JJ     48
#define NN     32
#define TT     48
#define DM     512
#define DEMB   300
#define DFIX   30000
#define DEXT   32000
#define SRC_TOT (LL + JJ + NN)      // 336
#define ROWS   (BS * TT)            // 384
#define NT     235                  // logits n-tiles (235*128 = 30080)
#define KH     320                  // Hh padded K (300 -> 320)

typedef float f32x4  __attribute__((ext_vector_type(4)));
typedef short bf16x8 __attribute__((ext_vector_type(8)));

__device__ __forceinline__ short f2bf(float f) {
    union { float f; unsigned u; } v; v.f = f;
    return (short)((v.u + 0x7FFFu + ((v.u >> 16) & 1u)) >> 16);  // RNE
}
__device__ __forceinline__ float bf2f(short s) {
    union { unsigned u; float f; } v;
    v.u = ((unsigned)(unsigned short)s) << 16;
    return v.f;
}
__device__ __forceinline__ float fast_exp2(float x) {
#if __has_builtin(__builtin_amdgcn_exp2f)
    return __builtin_amdgcn_exp2f(x);
#else
    return exp2f(x);
#endif
}
__device__ __forceinline__ float fast_rcp(float x) {
#if __has_builtin(__builtin_amdgcn_rcpf)
    return __builtin_amdgcn_rcpf(x);
#else
    return 1.f / x;
#endif
}
__device__ __forceinline__ float fast_tanh(float x) {
    x = fminf(fmaxf(x, -15.f), 15.f);
    const float e = fast_exp2(x * 2.885390082f);
    return (e - 1.f) * fast_rcp(e + 1.f);
}
__device__ __forceinline__ bool smask_true(const void* smask, bool byteLayout, int i)
{
    if (byteLayout) return ((const unsigned char*)smask)[i] != 0;
    return ((const int*)smask)[i] != 0;
}
__device__ __forceinline__ void mask8(const void* smask, bool byteLayout, int i,
                                      int* mb)
{
    if (byteLayout) {
        const uchar4 a = ((const uchar4*)((const unsigned char*)smask + i))[0];
        const uchar4 b = ((const uchar4*)((const unsigned char*)smask + i))[1];
        mb[0]=a.x; mb[1]=a.y; mb[2]=a.z; mb[3]=a.w;
        mb[4]=b.x; mb[5]=b.y; mb[6]=b.z; mb[7]=b.w;
    } else {
        const int* p = (const int*)smask + i;
        #pragma unroll
        for (int j = 0; j < 8; ++j) mb[j] = p[j];
    }
}

// ---------------------------------------------------------------------------
// Weight prep. Two modes:
//  ntx>0: W[K][N] fp32 -> Wt[N][Kp] bf16 transpose (zero-filled to Kp).
//  ntx==0: flat cast fp32 -> bf16, K = element count (multiple of 8).
// ---------------------------------------------------------------------------
struct PDesc { const float* src; short* dst; int K, N, Kp, ntx, tiles; };
struct PArgs { PDesc d[12]; int nd; };

__global__ __launch_bounds__(256) void prep_kernel(PArgs pa)
{
    __shared__ short T[64][72];
    int tile = blockIdx.x, g = 0;
    while (g + 1 < pa.nd && tile >= pa.d[g].tiles) { tile -= pa.d[g].tiles; ++g; }
    const PDesc d = pa.d[g];
    const int tid = threadIdx.x;

    if (d.ntx == 0) {                 // flat fp32 -> bf16 cast
        const int i = (tile * 256 + tid) * 8;
        if (i < d.K) {
            const float4 a = ((const float4*)(d.src + i))[0];
            const float4 b = ((const float4*)(d.src + i))[1];
            bf16x8 v;
            v[0]=f2bf(a.x); v[1]=f2bf(a.y); v[2]=f2bf(a.z); v[3]=f2bf(a.w);
            v[4]=f2bf(b.x); v[5]=f2bf(b.y); v[6]=f2bf(b.z); v[7]=f2bf(b.w);
            *(bf16x8*)&d.dst[i] = v;
        }
        return;
    }

    const int kt = tile / d.ntx, nt = tile % d.ntx;
    const int k0 = kt * 64, n0 = nt * 64;
    {
        const int n = n0 + (tid & 63);
        #pragma unroll
        for (int p = 0; p < 16; ++p) {
            const int kk = p * 4 + (tid >> 6);
            const int k = k0 + kk;
            float v = 0.f;
            if (k < d.K && n < d.N) v = d.src[(size_t)k * d.N + n];
            T[kk][tid & 63] = f2bf(v);
        }
    }
    __syncthreads();
    {
        const int nn = tid >> 2;          // 0..63
        const int kq = (tid & 3) * 16;    // 0,16,32,48
        const int n = n0 + nn;
        if (n < d.N) {
            bf16x8 v0, v1;
            #pragma unroll
            for (int j = 0; j < 8; ++j) v0[j] = T[kq + j][nn];
            #pragma unroll
            for (int j = 0; j < 8; ++j) v1[j] = T[kq + 8 + j][nn];
            *(bf16x8*)&d.dst[(size_t)n * d.Kp + k0 + kq]     = v0;
            *(bf16x8*)&d.dst[(size_t)n * d.Kp + k0 + kq + 8] = v1;
        }
    }
}

// ---------------------------------------------------------------------------
// Batched bf16-MFMA GEMM v5: C[M,N] = A[M,K]@B[K,N] (+bias).
// A is PRE-CAST bf16 [M][Kp] (padded, no bounds checks); B bf16 Wt[N][Kp].
// obf: 0 = fp32 C; 1 = bf16 C + fused masked softmax partials (pstat);
//      2 = bf16 C zero-padded to npad columns (row stride npad).
// 128x128 tile, BK=32, dbuf LDS (row pad 130 -> conflict-free staging).
// ---------------------------------------------------------------------------
struct GDesc { const short* A; const short* Bt; const float* bias; void* C;
               const void* smask; float* pstat;
               int M, N, K, Kp, nx, my, obf, npad, nt, tiles; };
struct GArgs { GDesc d[7]; int nd; };

__global__ __launch_bounds__(256) void gemm_bf16_kernel(GArgs ga)
{
    __shared__ short As[2][4][130][8];
    __shared__ short Bs[2][4][130][8];
    __shared__ float pm_s[128][2];
    __shared__ float ps_s[128][2];

    int tile = blockIdx.x, g = 0;
    while (g + 1 < ga.nd && tile >= ga.d[g].tiles) { tile -= ga.d[g].tiles; ++g; }
    const short* __restrict__ A  = ga.d[g].A;
    const short* __restrict__ Bt = ga.d[g].Bt;
    const float* bias = ga.d[g].bias;
    const int N = ga.d[g].N, Kp = ga.d[g].Kp;
    const int nx = ga.d[g].nx, my = ga.d[g].my, obf = ga.d[g].obf;
    const int npad = ga.d[g].npad;

    int bm, bn;
    if (my > 0) { bm = (tile % my) * 128; bn = (tile / my) * 128; }
    else        { bm = (tile / nx) * 128; bn = (tile % nx) * 128; }
    const int tid  = threadIdx.x;
    const int lane = tid & 63;
    const int wv   = tid >> 6;
    const int wm   = (wv >> 1) * 64;
    const int wn   = (wv & 1) * 64;

    bf16x8 ra[2], rb[2];

    auto loadA = [&](int k0) {
        #pragma unroll
        for (int p = 0; p < 2; ++p) {
            const int row = p * 64 + (tid >> 2);
            ra[p] = *(const bf16x8*)&A[(size_t)(bm + row) * Kp + k0 + (tid & 3) * 8];
        }
    };
    auto loadB = [&](int k0) {
        #pragma unroll
        for (int p = 0; p < 2; ++p) {
            const int idx = p * 256 + tid;
            const int n = idx >> 2, kb = idx & 3;
            const int gn = bn + n;
            bf16x8 v = {};
            if (gn < N) v = *(const bf16x8*)&Bt[(size_t)gn * Kp + k0 + kb * 8];
            rb[p] = v;
        }
    };
    auto storeA = [&](int buf) {
        const int kb = tid & 3;
        #pragma unroll
        for (int p = 0; p < 2; ++p)
            *(bf16x8*)&As[buf][kb][p * 64 + (tid >> 2)][0] = ra[p];
    };
    auto storeB = [&](int buf) {
        #pragma unroll
        for (int p = 0; p < 2; ++p) {
            const int idx = p * 256 + tid;
            const int n = idx >> 2, kb = idx & 3;
            *(bf16x8*)&Bs[buf][kb][n][0] = rb[p];
        }
    };

    f32x4 acc[4][4] = {};
    const int nk = Kp / 32;

    loadA(0); loadB(0);
    storeA(0); storeB(0);
    __syncthreads();

    for (int kk = 0; kk < nk; ++kk) {
        const int cur = kk & 1;
        if (kk + 1 < nk) { loadA((kk + 1) * 32); loadB((kk + 1) * 32); }
        bf16x8 af[4], bfr[4];
        #pragma unroll
        for (int i = 0; i < 4; ++i) {
            af[i]  = *(const bf16x8*)&As[cur][lane >> 4][wm + i * 16 + (lane & 15)][0];
            bfr[i] = *(const bf16x8*)&Bs[cur][lane >> 4][wn + i * 16 + (lane & 15)][0];
        }
        #pragma unroll
        for (int mi = 0; mi < 4; ++mi)
            #pragma unroll
            for (int ni = 0; ni < 4; ++ni)
                acc[mi][ni] = __builtin_amdgcn_mfma_f32_16x16x32_bf16(
                    af[mi], bfr[ni], acc[mi][ni], 0, 0, 0);
        if (kk + 1 < nk) { storeA(cur ^ 1); storeB(cur ^ 1); }
        __syncthreads();
    }

    if (obf == 0) {
        float* Cf = (float*)ga.d[g].C;
        #pragma unroll
        for (int ni = 0; ni < 4; ++ni) {
            const int gn = bn + wn + ni * 16 + (lane & 15);
            if (gn >= N) continue;
            const float bb = bias ? bias[gn] : 0.f;
            #pragma unroll
            for (int mi = 0; mi < 4; ++mi)
                #pragma unroll
                for (int r = 0; r < 4; ++r) {
                    const int gm = bm + wm + mi * 16 + (lane >> 4) * 4 + r;
                    Cf[(size_t)gm * N + gn] = acc[mi][ni][r] + bb;
                }
        }
    } else if (obf == 2) {
        // bf16 C, zero-padded to npad columns, row stride npad
        short* Cs = (short*)ga.d[g].C;
        #pragma unroll
        for (int ni = 0; ni < 4; ++ni) {
            const int gn = bn + wn + ni * 16 + (lane & 15);
            if (gn >= npad) continue;
            const bool valid = (gn < N);
            const float bb = (valid && bias) ? bias[gn] : 0.f;
            #pragma unroll
            for (int mi = 0; mi < 4; ++mi)
                #pragma unroll
                for (int r = 0; r < 4; ++r) {
                    const int gm = bm + wm + mi * 16 + (lane >> 4) * 4 + r;
                    Cs[(size_t)gm * npad + gn] = valid ? f2bf(acc[mi][ni][r] + bb) : (short)0;
                }
        }
    } else {
        // bf16 C write + fused masked softmax partials (no bias on this path)
        short* Cs = (short*)ga.d[g].C;
        const void* sm = ga.d[g].smask;
        const bool byteLayout = (((const int*)sm)[1] == 0x01010101);
        int mk[4];
        #pragma unroll
        for (int ni = 0; ni < 4; ++ni) {
            const int gn = bn + wn + ni * 16 + (lane & 15);
            const bool inb = (gn < N);
            mk[ni] = inb && smask_true(sm, byteLayout, inb ? gn : 0);
            if (inb) {
                #pragma unroll
                for (int mi = 0; mi < 4; ++mi)
                    #pragma unroll
                    for (int r = 0; r < 4; ++r) {
                        const int gm = bm + wm + mi * 16 + (lane >> 4) * 4 + r;
                        Cs[(size_t)gm * N + gn] = f2bf(acc[mi][ni][r]);
                    }
            }
        }
        #pragma unroll
        for (int mi = 0; mi < 4; ++mi) {
            #pragma unroll
            for (int r = 0; r < 4; ++r) {
                const int rl = wm + mi * 16 + (lane >> 4) * 4 + r;  // 0..127
                float vmax = -INFINITY;
                #pragma unroll
                for (int ni = 0; ni < 4; ++ni)
                    if (mk[ni]) vmax = fmaxf(vmax, acc[mi][ni][r]);
                #pragma unroll
                for (int o = 1; o < 16; o <<= 1)
                    vmax = fmaxf(vmax, __shfl_xor(vmax, o));
                float se = 0.f;
                #pragma unroll
                for (int ni = 0; ni < 4; ++ni)
                    if (mk[ni]) se += __expf(acc[mi][ni][r] - vmax);
                #pragma unroll
                for (int o = 1; o < 16; o <<= 1)
                    se += __shfl_xor(se, o);
                if ((lane & 15) == 0) {
                    pm_s[rl][wn >> 6] = vmax;
                    ps_s[rl][wn >> 6] = se;
                }
            }
        }
        __syncthreads();
        if (tid < 128) {
            const float mA = pm_s[tid][0], mB = pm_s[tid][1];
            const float sA = ps_s[tid][0], sB = ps_s[tid][1];
            const float m = fmaxf(mA, mB);
            float s = 0.f;
            if (sA > 0.f) s += sA * __expf(mA - m);
            if (sB > 0.f) s += sB * __expf(mB - m);
            float* ps = ga.d[g].pstat;
            const size_t idx = ((size_t)(bm + tid) * ga.d[g].nt + (bn >> 7)) * 2;
            ps[idx + 0] = m;
            ps[idx + 1] = s;
        }
    }
}

// ---------------------------------------------------------------------------
// Attention scores, load-balanced: grid (ROWS, 6 chunks), 256 threads.
// ---------------------------------------------------------------------------
struct SDesc { const float* Kp; const float* Qp; const float* vv;
               int Sb, s0, cnt, off; };
struct SArgs { SDesc c[6]; };

__global__ __launch_bounds__(256) void scores_kernel(SArgs sa,
                                                     float* __restrict__ scb)
{
    const SDesc d = sa.c[blockIdx.y];
    const int bt   = blockIdx.x;
    const int b    = bt / TT;
    const int tid  = threadIdx.x;
    const int lane = tid & 63;
    const int wave = tid >> 6;

    float qp[8], vv[8];
    {
        const float4* q4 = (const float4*)(d.Qp + (size_t)bt * DM) + lane * 2;
        float4 a = q4[0], c = q4[1];
        qp[0]=a.x; qp[1]=a.y; qp[2]=a.z; qp[3]=a.w;
        qp[4]=c.x; qp[5]=c.y; qp[6]=c.z; qp[7]=c.w;
        const float4* v4 = (const float4*)d.vv + lane * 2;
        a = v4[0]; c = v4[1];
        vv[0]=a.x; vv[1]=a.y; vv[2]=a.z; vv[3]=a.w;
        vv[4]=c.x; vv[5]=c.y; vv[6]=c.z; vv[7]=c.w;
    }
    for (int s = wave; s < d.cnt; s += 4) {
        const float* krow = d.Kp + ((size_t)b * d.Sb + d.s0 + s) * DM + lane * 8;
        const float4 ka = ((const float4*)krow)[0];
        const float4 kb = ((const float4*)krow)[1];
        float acc = 0.f;
        acc = fmaf(vv[0], fast_tanh(qp[0] + ka.x), acc);
        acc = fmaf(vv[1], fast_tanh(qp[1] + ka.y), acc);
        acc = fmaf(vv[2], fast_tanh(qp[2] + ka.z), acc);
        acc = fmaf(vv[3], fast_tanh(qp[3] + ka.w), acc);
        acc = fmaf(vv[4], fast_tanh(qp[4] + kb.x), acc);
        acc = fmaf(vv[5], fast_tanh(qp[5] + kb.y), acc);
        acc = fmaf(vv[6], fast_tanh(qp[6] + kb.z), acc);
        acc = fmaf(vv[7], fast_tanh(qp[7] + kb.w), acc);
        #pragma unroll
        for (int off = 32; off; off >>= 1) acc += __shfl_xor(acc, off);
        if (lane == 0) scb[(size_t)bt * SRC_TOT + d.off + s] = acc;
    }
}

// ---------------------------------------------------------------------------
// Merged attention-finish + mixture + stats-combine: one block (512) per (b,t).
// ctx reads the bf16 copies of Mq/Mqa/Mp (halved traffic).
// ---------------------------------------------------------------------------
__global__ __launch_bounds__(512) void attn2mix_kernel(
    const float* __restrict__ scb,
    const short* __restrict__ Mqb, const short* __restrict__ Mqab,
    const short* __restrict__ Mpb, const float* __restrict__ Mnlg,
    const float* __restrict__ Wm, const float* __restrict__ bm,
    const float* __restrict__ pstat,
    float* __restrict__ dQ, float* __restrict__ dQA, float* __restrict__ dP,
    float* __restrict__ lam_ws, float* __restrict__ lam_out,
    float* __restrict__ stat)
{
    __shared__ float a_sh[SRC_TOT];
    __shared__ float cQ[DM], cA[DM], cP[DM];
    __shared__ float red[16];
    __shared__ float redm[32];
    __shared__ float s_lamv;
    const int bt   = blockIdx.x;
    const int b    = bt / TT;
    const int tid  = threadIdx.x;
    const int lane = tid & 63;
    const int wave = tid >> 6;          // 0..7
    const float* srow = scb + (size_t)bt * SRC_TOT;

    #pragma unroll
    for (int br = 0; br < 3; ++br) {
        const int off = (br == 0) ? 0 : (br == 1) ? JJ : (JJ + NN);
        const int cnt = (br == 0) ? JJ : (br == 1) ? NN : LL;
        float x = (tid < cnt) ? srow[off + tid] : -INFINITY;
        float m = x;
        #pragma unroll
        for (int o = 32; o; o >>= 1) m = fmaxf(m, __shfl_xor(m, o));
        if (lane == 0) red[wave] = m;
        __syncthreads();
        m = red[0];
        #pragma unroll
        for (int w = 1; w < 8; ++w) m = fmaxf(m, red[w]);
        float e = (tid < cnt) ? __expf(x - m) : 0.f;
        float ss = e;
        #pragma unroll
        for (int o = 32; o; o >>= 1) ss += __shfl_xor(ss, o);
        if (lane == 0) red[8 + wave] = ss;
        __syncthreads();
        float denom = 0.f;
        #pragma unroll
        for (int w = 0; w < 8; ++w) denom += red[8 + w];
        if (tid < cnt) {
            const float a = e / denom;
            a_sh[off + tid] = a;
            float* dst = (br == 0) ? dQ : (br == 1) ? dQA : dP;
            dst[(size_t)bt * cnt + tid] = a;
        }
        __syncthreads();
    }
    // ctx for d = tid (0..511), kept in LDS (bf16 V reads)
    {
        float aQ = 0.f, aA = 0.f, aP = 0.f;
        for (int s = 0; s < JJ; ++s)
            aQ = fmaf(a_sh[s],           bf2f(Mqb [((size_t)b * JJ + s) * DM + tid]), aQ);
        for (int s = 0; s < NN; ++s)
            aA = fmaf(a_sh[JJ + s],      bf2f(Mqab[((size_t)b * NN + s) * DM + tid]), aA);
        for (int s = 0; s < LL; ++s)
            aP = fmaf(a_sh[JJ + NN + s], bf2f(Mpb [((size_t)b * LL + s) * DM + tid]), aP);
        cQ[tid] = aQ; cA[tid] = aA; cP[tid] = aP;
    }
    __syncthreads();
    // mix: thread handles k = tid, tid+512, tid+1024, tid+1536
    {
        const float x0 = Mnlg[(size_t)bt * DM + tid];
        const float x1 = cQ[tid], x2 = cA[tid], x3 = cP[tid];
        const float4 w0 = *(const float4*)&Wm[(size_t)tid * 4];
        const float4 w1 = *(const float4*)&Wm[(size_t)(512 + tid) * 4];
        const float4 w2 = *(const float4*)&Wm[(size_t)(1024 + tid) * 4];
        const float4 w3 = *(const float4*)&Wm[(size_t)(1536 + tid) * 4];
        float acc[4];
        acc[0] = x0 * w0.x + x1 * w1.x + x2 * w2.x + x3 * w3.x;
        acc[1] = x0 * w0.y + x1 * w1.y + x2 * w2.y + x3 * w3.y;
        acc[2] = x0 * w0.z + x1 * w1.z + x2 * w2.z + x3 * w3.z;
        acc[3] = x0 * w0.w + x1 * w1.w + x2 * w2.w + x3 * w3.w;
        #pragma unroll
        for (int c = 0; c < 4; ++c)
            #pragma unroll
            for (int o = 32; o; o >>= 1) acc[c] += __shfl_xor(acc[c], o);
        if (lane == 0) {
            redm[wave * 4 + 0] = acc[0]; redm[wave * 4 + 1] = acc[1];
            redm[wave * 4 + 2] = acc[2]; redm[wave * 4 + 3] = acc[3];
        }
        __syncthreads();
        if (tid == 0) {
            float l[4];
            #pragma unroll
            for (int c = 0; c < 4; ++c) {
                float s = bm[c];
                #pragma unroll
                for (int w = 0; w < 8; ++w) s += redm[w * 4 + c];
                l[c] = s;
            }
            const float mx = fmaxf(fmaxf(l[0], l[1]), fmaxf(l[2], l[3]));
            const float e0 = __expf(l[0] - mx), e1 = __expf(l[1] - mx);
            const float e2 = __expf(l[2] - mx), e3 = __expf(l[3] - mx);
            const float inv = 1.f / (e0 + e1 + e2 + e3);
            s_lamv = e0 * inv;
            lam_ws[bt * 4 + 0] = e0 * inv; lam_out[bt * 4 + 0] = e0 * inv;
            lam_ws[bt * 4 + 1] = e1 * inv; lam_out[bt * 4 + 1] = e1 * inv;
            lam_ws[bt * 4 + 2] = e2 * inv; lam_out[bt * 4 + 2] = e2 * inv;
            lam_ws[bt * 4 + 3] = e3 * inv; lam_out[bt * 4 + 3] = e3 * inv;
        }
    }
    __syncthreads();
    // stats-combine for this row (wave 0 only)
    if (wave == 0) {
        float m = -INFINITY;
        for (int c = lane; c < NT; c += 64)
            m = fmaxf(m, pstat[((size_t)bt * NT + c) * 2]);
        #pragma unroll
        for (int o = 32; o; o >>= 1) m = fmaxf(m, __shfl_xor(m, o));
        float s = 0.f;
        for (int c = lane; c < NT; c += 64) {
            const float pm = pstat[((size_t)bt * NT + c) * 2];
            const float ps = pstat[((size_t)bt * NT + c) * 2 + 1];
            if (ps > 0.f) s += ps * __expf(pm - m);
        }
        #pragma unroll
        for (int o = 32; o; o >>= 1) s += __shfl_xor(s, o);
        if (lane == 0) {
            stat[bt * 2 + 0] = m;
            stat[bt * 2 + 1] = s_lamv / s;
        }
    }
}

// ---------------------------------------------------------------------------
// Merged row write + scatter: one block (1024 thr) per row; stat precombined.
// ---------------------------------------------------------------------------
__global__ __launch_bounds__(1024) void writescatter_kernel(
    const short* __restrict__ logits, const void* __restrict__ smask,
    const float* __restrict__ stat, const float* __restrict__ lam,
    const float* __restrict__ dP, const float* __restrict__ dQ,
    const float* __restrict__ dQA, const void* __restrict__ src_ext,
    float* __restrict__ out)
{
    const bool byteLayout = (((const int*)smask)[1] == 0x01010101);
    const int r = blockIdx.x;
    const float m   = stat[r * 2 + 0];
    const float inv = stat[r * 2 + 1];

    const short* lrow = logits + (size_t)r * DFIX;
    float* orow = out + (size_t)r * DEXT;
    const int tid = threadIdx.x;
    #pragma unroll
    for (int k = 0; k < 4; ++k) {
        const int i = (k * 1024 + tid) * 8;
        if (i >= DEXT) continue;
        float4 o0 = make_float4(0.f, 0.f, 0.f, 0.f);
        float4 o1 = make_float4(0.f, 0.f, 0.f, 0.f);
        if (i < DFIX) {                 // 30000 % 8 == 0: no straddle
            const bf16x8 v = *(const bf16x8*)&lrow[i];
            int mb[8]; mask8(smask, byteLayout, i, mb);
            o0.x = mb[0] ? __expf(bf2f(v[0]) - m) * inv : 0.f;
            o0.y = mb[1] ? __expf(bf2f(v[1]) - m) * inv : 0.f;
            o0.z = mb[2] ? __expf(bf2f(v[2]) - m) * inv : 0.f;
            o0.w = mb[3] ? __expf(bf2f(v[3]) - m) * inv : 0.f;
            o1.x = mb[4] ? __expf(bf2f(v[4]) - m) * inv : 0.f;
            o1.y = mb[5] ? __expf(bf2f(v[5]) - m) * inv : 0.f;
            o1.z = mb[6] ? __expf(bf2f(v[6]) - m) * inv : 0.f;
            o1.w = mb[7] ? __expf(bf2f(v[7]) - m) * inv : 0.f;
        }
        *(float4*)&orow[i]     = o0;
        *(float4*)&orow[i + 4] = o1;
    }
    __syncthreads();
    if (tid < SRC_TOT) {
        const int* s32 = (const int*)src_ext;
        const bool src64 = (s32[1] == 0 && s32[3] == 0 && s32[5] == 0 && s32[7] == 0);
        const int b = r / TT;
        const float lamq  = lam[r * 4 + 1];
        const float lamqa = lam[r * 4 + 2];
        const float lamp  = lam[r * 4 + 3];
        const int pos = b * SRC_TOT + tid;
        const int idx = src64 ? (int)((const long long*)src_ext)[pos] : s32[pos];
        float val;
        if      (tid < LL)      val = dP [(size_t)r * LL + tid]             * lamp;
        else if (tid < LL + JJ) val = dQ [(size_t)r * JJ + (tid - LL)]      * lamq;
        else                    val = dQA[(size_t)r * NN + (tid - LL - JJ)] * lamqa;
        atomicAdd(&orow[idx], val);
    }
}

// ---------------------------------------------------------------------------
extern "C" void kernel_launch(void* const* d_in, const int* in_sizes, int n_in,
                              void* d_out, int out_size, void* d_ws, size_t ws_size,
                              hipStream_t stream)
{
    const float* Mp   = (const float*)d_in[0];
    const float* Mq   = (const float*)d_in[1];
    const float* Mqa  = (const float*)d_in[2];
    const float* Mnlg = (const float*)d_in[3];
    const void* src_ext = d_in[7];
    const void* smask   = d_in[8];
    const float* Wk_q = (const float*)d_in[10];
    const float* bk_q = (const float*)d_in[11];
    const float* Wq_q = (const float*)d_in[12];
    const float* bq_q = (const float*)d_in[13];
    const float* v_q  = (const float*)d_in[14];
    const float* Wk_a = (const float*)d_in[15];
    const float* bk_a = (const float*)d_in[16];
    const float* Wq_a = (const float*)d_in[17];
    const float* bq_a = (const float*)d_in[18];
    const float* v_a  = (const float*)d_in[19];
    const float* Wk_p = (const float*)d_in[20];
    const float* bk_p = (const float*)d_in[21];
    const float* Wq_p = (const float*)d_in[22];
    const float* bq_p = (const float*)d_in[23];
    const float* v_p  = (const float*)d_in[24];
    const float* W1   = (const float*)d_in[25];
    const float* b1   = (const float*)d_in[26];
    const float* W2   = (const float*)d_in[27];
    const float* Wm   = (const float*)d_in[28];
    const float* bm   = (const float*)d_in[29];
    float* out = (float*)d_out;

    char* ws = (char*)d_ws;
    size_t off = 0;
    auto alloc = [&](size_t bytes) -> char* {
        char* p = ws + off;
        off += (bytes + 255) & ~(size_t)255;
        return p;
    };
    short* logits = (short*)alloc((size_t)ROWS * DFIX * 2);   // bf16
    float* KpP    = (float*)alloc((size_t)BS * LL * DM * 4);
    float* KpQ    = (float*)alloc((size_t)BS * JJ * DM * 4);
    float* KpA    = (float*)alloc((size_t)BS * NN * DM * 4);
    float* QpQ    = (float*)alloc((size_t)ROWS * DM * 4);
    float* QpA    = (float*)alloc((size_t)ROWS * DM * 4);
    float* QpP    = (float*)alloc((size_t)ROWS * DM * 4);
    float* dP     = (float*)alloc((size_t)ROWS * LL * 4);
    float* dQ     = (float*)alloc((size_t)ROWS * JJ * 4);
    float* dQA    = (float*)alloc((size_t)ROWS * NN * 4);
    float* lam    = (float*)alloc((size_t)ROWS * 4 * 4);
    float* pstat  = (float*)alloc((size_t)ROWS * NT * 2 * 4);
    float* stat   = (float*)alloc((size_t)ROWS * 2 * 4);
    float* scb    = (float*)alloc((size_t)ROWS * SRC_TOT * 4);
    short* tWkq = (short*)alloc((size_t)DM * DM * 2);
    short* tWqq = (short*)alloc((size_t)DM * DM * 2);
    short* tWka = (short*)alloc((size_t)DM * DM * 2);
    short* tWqa = (short*)alloc((size_t)DM * DM * 2);
    short* tWkp = (short*)alloc((size_t)DM * DM * 2);
    short* tWqp = (short*)alloc((size_t)DM * DM * 2);
    short* tW1  = (short*)alloc((size_t)DEMB * DM * 2);
    short* tW2  = (short*)alloc((size_t)DFIX * KH * 2);
    short* Mp_bf   = (short*)alloc((size_t)BS * LL * DM * 2);
    short* Mq_bf   = (short*)alloc((size_t)BS * JJ * DM * 2);
    short* Mqa_bf  = (short*)alloc((size_t)BS * NN * DM * 2);
    short* Mnlg_bf = (short*)alloc((size_t)ROWS * DM * 2);
    short* Hh_bf   = (short*)alloc((size_t)ROWS * KH * 2);
    (void)ws_size; (void)in_sizes; (void)n_in; (void)out_size;

    // ---- prep: transpose+cast weights AND flat-cast activations to bf16
    PArgs pa;
    pa.nd = 12;
    pa.d[0]  = { Wk_p, tWkp, DM,   DM,   DM,  8,  64 };
    pa.d[1]  = { Wk_q, tWkq, DM,   DM,   DM,  8,  64 };
    pa.d[2]  = { Wk_a, tWka, DM,   DM,   DM,  8,  64 };
    pa.d[3]  = { Wq_q, tWqq, DM,   DM,   DM,  8,  64 };
    pa.d[4]  = { Wq_a, tWqa, DM,   DM,   DM,  8,  64 };
    pa.d[5]  = { Wq_p, tWqp, DM,   DM,   DM,  8,  64 };
    pa.d[6]  = { W1,   tW1,  DM,   DEMB, DM,  5,  40 };
    pa.d[7]  = { W2,   tW2,  DEMB, DFIX, KH,  469, 2345 };
    pa.d[8]  = { Mp,   Mp_bf,   BS*LL*DM, 0, 0, 0, (BS*LL*DM) / 2048 };   // 512
    pa.d[9]  = { Mq,   Mq_bf,   BS*JJ*DM, 0, 0, 0, (BS*JJ*DM) / 2048 };   // 96
    pa.d[10] = { Mqa,  Mqa_bf,  BS*NN*DM, 0, 0, 0, (BS*NN*DM) / 2048 };   // 64
    pa.d[11] = { Mnlg, Mnlg_bf, ROWS*DM,  0, 0, 0, (ROWS*DM) / 2048 };    // 96
    prep_kernel<<<64 * 6 + 40 + 2345 + 512 + 96 + 64 + 96, 256, 0, stream>>>(pa);

    // ---- launch A: Hh_bf = bf16( Mnlg @ W1 + b1 ), zero-padded to KH cols
    GArgs gA;
    gA.nd = 1;
    gA.d[0] = { Mnlg_bf, tW1, b1, Hh_bf, nullptr, nullptr,
                ROWS, DEMB, DM, DM, 3, 0, 2, KH, 0, 9 };
    gemm_bf16_kernel<<<9, 256, 0, stream>>>(gA);

    // ---- launch B: projections (long-K) first, logits (fused stats) last
    GArgs gB;
    gB.nd = 7;
    gB.d[0] = { Mp_bf,   tWkp, bk_p,    KpP,    nullptr, nullptr,
                BS*LL, DM,   DM,   DM,  4,   0, 0, DM,   0,  64 };
    gB.d[1] = { Mq_bf,   tWkq, bk_q,    KpQ,    nullptr, nullptr,
                BS*JJ, DM,   DM,   DM,  4,   0, 0, DM,   0,  12 };
    gB.d[2] = { Mqa_bf,  tWka, bk_a,    KpA,    nullptr, nullptr,
                BS*NN, DM,   DM,   DM,  4,   0, 0, DM,   0,   8 };
    gB.d[3] = { Mnlg_bf, tWqq, bq_q,    QpQ,    nullptr, nullptr,
                ROWS,  DM,   DM,   DM,  4,   0, 0, DM,   0,  12 };
    gB.d[4] = { Mnlg_bf, tWqa, bq_a,    QpA,    nullptr, nullptr,
                ROWS,  DM,   DM,   DM,  4,   0, 0, DM,   0,  12 };
    gB.d[5] = { Mnlg_bf, tWqp, bq_p,    QpP,    nullptr, nullptr,
                ROWS,  DM,   DM,   DM,  4,   0, 0, DM,   0,  12 };
    gB.d[6] = { Hh_bf,   tW2,  nullptr, logits, smask,   pstat,
                ROWS,  DFIX, DEMB, KH,  235, 3, 1, DFIX, NT, 705 };
    gemm_bf16_kernel<<<825, 256, 0, stream>>>(gB);

    // ---- attention: load-balanced scores, then finish+mix+combine
    SArgs sa;
    sa.c[0] = { KpQ, QpQ, v_q, JJ,   0, JJ,  0 };
    sa.c[1] = { KpA, QpA, v_a, NN,   0, NN,  JJ };
    sa.c[2] = { KpP, QpP, v_p, LL,   0, 64,  JJ + NN };
    sa.c[3] = { KpP, QpP, v_p, LL,  64, 64,  JJ + NN + 64 };
    sa.c[4] = { KpP, QpP, v_p, LL, 128, 64,  JJ + NN + 128 };
    sa.c[5] = { KpP, QpP, v_p, LL, 192, 64,  JJ + NN + 192 };
    scores_kernel<<<dim3(ROWS, 6), 256, 0, stream>>>(sa, scb);
    attn2mix_kernel<<<ROWS, 512, 0, stream>>>(scb, Mq_bf, Mqa_bf, Mp_bf, Mnlg,
                                              Wm, bm, pstat, dQ, dQA, dP, lam,
                                              out + (size_t)ROWS * DEXT, stat);

    // ---- merged row write + scatter
    writescatter_kernel<<<ROWS, 1024, 0, stream>>>(
        logits, smask, stat, lam, dP, dQ, dQA, src_ext, out);
}